// Round 1
// baseline (4398.526 us; speedup 1.0000x reference)
//
#include <hip/hip_runtime.h>
#include <hip/hip_bf16.h>

#define NODES_PER_BLOCK 32

// ---------------- degree: deg[dst[e]] += 1 ----------------
__global__ __launch_bounds__(256) void deg_kernel(const int* __restrict__ dst,
                                                  float* __restrict__ deg, int E) {
    int e = blockIdx.x * 256 + threadIdx.x;
    if (e >= E) return;
    atomicAdd(&deg[dst[e]], 1.0f);
}

// ---------------- scatter: agg[dst[e]] += x[src[e]] ----------------
// 16 threads per edge, each handles 4 contiguous channels (float4 gather).
__global__ __launch_bounds__(256) void scatter_kernel(const float* __restrict__ x,
                                                      const int* __restrict__ src,
                                                      const int* __restrict__ dst,
                                                      float* __restrict__ agg, int E) {
    int gid = blockIdx.x * 256 + threadIdx.x;
    int e = gid >> 4;
    if (e >= E) return;
    int c = (gid & 15) << 2;
    int s = src[e];
    int d = dst[e];
    const float4 v = *(const float4*)(x + (size_t)s * 64 + c);
    float* a = agg + (size_t)d * 64 + c;
    atomicAdd(a + 0, v.x);
    atomicAdd(a + 1, v.y);
    atomicAdd(a + 2, v.z);
    atomicAdd(a + 3, v.w);
}

// ---------------- update: out = x@Wself + (agg/deg)@Wnei + b (opt relu) ----------------
// 256 threads, 32 nodes/block; thread t: node t>>3, output cols (t&7)*8 .. +7.
__global__ __launch_bounds__(256) void update_kernel(const float* __restrict__ xin,
                                                     const float* __restrict__ agg,
                                                     const float* __restrict__ deg,
                                                     const float* __restrict__ Wself,
                                                     const float* __restrict__ Wnei,
                                                     const float* __restrict__ bias,
                                                     float* __restrict__ out,
                                                     int n_nodes, int do_relu) {
    __shared__ float sWs[64 * 64];
    __shared__ float sWn[64 * 64];
    __shared__ float sb[64];
    __shared__ float sx[NODES_PER_BLOCK][65];   // +1 pad: bank-conflict-free column reads
    __shared__ float sm[NODES_PER_BLOCK][65];

    const int tid = threadIdx.x;
    for (int i = tid; i < 4096; i += 256) {
        sWs[i] = Wself[i];
        sWn[i] = Wnei[i];
    }
    if (tid < 64) sb[tid] = bias[tid];

    const int node0 = blockIdx.x * NODES_PER_BLOCK;
    for (int i = tid; i < NODES_PER_BLOCK * 64; i += 256) {
        int n = i >> 6, c = i & 63;
        int node = node0 + n;
        float xv = 0.f, mv = 0.f;
        if (node < n_nodes) {
            xv = xin[(size_t)node * 64 + c];
            float rd = 1.0f / fmaxf(deg[node], 1.0f);
            mv = agg[(size_t)node * 64 + c] * rd;
        }
        sx[n][c] = xv;
        sm[n][c] = mv;
    }
    __syncthreads();

    const int n = tid >> 3;
    const int j0 = (tid & 7) * 8;
    float acc[8];
#pragma unroll
    for (int jj = 0; jj < 8; jj++) acc[jj] = sb[j0 + jj];

    for (int k = 0; k < 64; k++) {
        float xv = sx[n][k];
        float mv = sm[n][k];
        const float* ws = &sWs[k * 64 + j0];
        const float* wn = &sWn[k * 64 + j0];
#pragma unroll
        for (int jj = 0; jj < 8; jj++) {
            acc[jj] += xv * ws[jj] + mv * wn[jj];
        }
    }

    const int node = node0 + n;
    if (node < n_nodes) {
#pragma unroll
        for (int jj = 0; jj < 8; jj++) {
            float v = acc[jj];
            if (do_relu) v = fmaxf(v, 0.f);
            out[(size_t)node * 64 + j0 + jj] = v;
        }
    }
}

extern "C" void kernel_launch(void* const* d_in, const int* in_sizes, int n_in,
                              void* d_out, int out_size, void* d_ws, size_t ws_size,
                              hipStream_t stream) {
    const float* x   = (const float*)d_in[0];
    const int*   ei  = (const int*)d_in[1];
    const float* ws1 = (const float*)d_in[2];
    const float* wn1 = (const float*)d_in[3];
    const float* b1  = (const float*)d_in[4];
    const float* ws2 = (const float*)d_in[5];
    const float* wn2 = (const float*)d_in[6];
    const float* b2  = (const float*)d_in[7];
    const float* ws3 = (const float*)d_in[8];
    const float* wn3 = (const float*)d_in[9];
    const float* b3  = (const float*)d_in[10];

    const int N = in_sizes[0] / 64;        // 100000
    const int E = in_sizes[1] / 2;         // 1600000
    const int* src = ei;
    const int* dst = ei + E;

    float* out = (float*)d_out;            // also doubles as h1 temp
    char*  ws  = (char*)d_ws;
    float* deg = (float*)ws;                                   // N floats
    float* agg = (float*)(ws + ((size_t)N * 4 + 255) / 256 * 256);  // N*64 floats
    float* h2  = agg + (size_t)N * 64;                         // N*64 floats

    const int deg_blocks  = (E + 255) / 256;
    const int scat_blocks = (E * 16 + 255) / 256;
    const int upd_blocks  = (N + NODES_PER_BLOCK - 1) / NODES_PER_BLOCK;

    // degree (shared across layers)
    hipMemsetAsync(deg, 0, (size_t)N * 4, stream);
    deg_kernel<<<deg_blocks, 256, 0, stream>>>(dst, deg, E);

    // layer 1: x -> out (h1), relu
    hipMemsetAsync(agg, 0, (size_t)N * 64 * 4, stream);
    scatter_kernel<<<scat_blocks, 256, 0, stream>>>(x, src, dst, agg, E);
    update_kernel<<<upd_blocks, 256, 0, stream>>>(x, agg, deg, ws1, wn1, b1, out, N, 1);

    // layer 2: out (h1) -> h2, relu
    hipMemsetAsync(agg, 0, (size_t)N * 64 * 4, stream);
    scatter_kernel<<<scat_blocks, 256, 0, stream>>>(out, src, dst, agg, E);
    update_kernel<<<upd_blocks, 256, 0, stream>>>(out, agg, deg, ws2, wn2, b2, h2, N, 1);

    // layer 3: h2 -> out, no relu
    hipMemsetAsync(agg, 0, (size_t)N * 64 * 4, stream);
    scatter_kernel<<<scat_blocks, 256, 0, stream>>>(h2, src, dst, agg, E);
    update_kernel<<<upd_blocks, 256, 0, stream>>>(h2, agg, deg, ws3, wn3, b3, out, N, 0);
}

// Round 2
// 755.752 us; speedup vs baseline: 5.8201x; 5.8201x over previous
//
#include <hip/hip_runtime.h>
#include <hip/hip_bf16.h>

#define NPB 32  // nodes per block in fused layer kernel

// ---------- CSR build ----------
__global__ __launch_bounds__(256) void count_kernel(const int* __restrict__ dst,
                                                    int* __restrict__ cnt, int E) {
    int e = blockIdx.x * 256 + threadIdx.x;
    if (e < E) atomicAdd(&cnt[dst[e]], 1);
}

// per-block exclusive scan of cnt -> excl (row_start, partial), block totals -> bsums
__global__ __launch_bounds__(256) void scan1_kernel(const int* __restrict__ cnt,
                                                    int* __restrict__ excl,
                                                    int* __restrict__ bsums, int N) {
    __shared__ int tmp[256];
    const int tid = threadIdx.x;
    const int g = blockIdx.x * 256 + tid;
    int v = (g < N) ? cnt[g] : 0;
    tmp[tid] = v;
    __syncthreads();
    for (int off = 1; off < 256; off <<= 1) {
        int t = (tid >= off) ? tmp[tid - off] : 0;
        __syncthreads();
        tmp[tid] += t;
        __syncthreads();
    }
    if (g < N) excl[g] = tmp[tid] - v;
    if (tid == 255) bsums[blockIdx.x] = tmp[255];
}

// exclusive scan of block sums (nb <= 512), single block
__global__ __launch_bounds__(512) void scan2_kernel(int* bsums, int nb) {
    __shared__ int tmp[512];
    const int tid = threadIdx.x;
    int v = (tid < nb) ? bsums[tid] : 0;
    tmp[tid] = v;
    __syncthreads();
    for (int off = 1; off < 512; off <<= 1) {
        int t = (tid >= off) ? tmp[tid - off] : 0;
        __syncthreads();
        tmp[tid] += t;
        __syncthreads();
    }
    if (tid < nb) bsums[tid] = tmp[tid] - v;  // exclusive
}

// add block offsets in place; clone into cursor; write row_start[N]=E
__global__ __launch_bounds__(256) void scan3_kernel(int* __restrict__ row_start,
                                                    int* __restrict__ cursor,
                                                    const int* __restrict__ bsums,
                                                    int N, int E) {
    const int g = blockIdx.x * 256 + threadIdx.x;
    if (g < N) {
        int v = row_start[g] + bsums[g >> 8];
        row_start[g] = v;
        cursor[g] = v;
    }
    if (g == 0) row_start[N] = E;
}

__global__ __launch_bounds__(256) void fill_kernel(const int* __restrict__ src,
                                                   const int* __restrict__ dst,
                                                   int* __restrict__ cursor,
                                                   int* __restrict__ col, int E) {
    int e = blockIdx.x * 256 + threadIdx.x;
    if (e >= E) return;
    int slot = atomicAdd(&cursor[dst[e]], 1);
    col[slot] = src[e];
}

// ---------- fused layer: gather-mean + out = x@Ws + mean@Wn + b (opt relu) ----------
// 256 threads, NPB=32 nodes/block.
// Gather: 16 lanes per node (each lane owns 4 channels), 2 rounds of 16 nodes.
// GEMM:   thread t -> node t>>3, output cols (t&7)*8 .. +7.
__global__ __launch_bounds__(256) void sage_layer_kernel(
        const float* __restrict__ xin, const int* __restrict__ col,
        const int* __restrict__ row_start,
        const float* __restrict__ Ws, const float* __restrict__ Wn,
        const float* __restrict__ bias, float* __restrict__ out,
        int N, int do_relu) {
    __shared__ float sWs[4096];
    __shared__ float sWn[4096];
    __shared__ float sb[64];
    __shared__ float sx[NPB][68];
    __shared__ float sm[NPB][68];

    const int tid = threadIdx.x;
    for (int i = tid; i < 4096; i += 256) {
        sWs[i] = Ws[i];
        sWn[i] = Wn[i];
    }
    if (tid < 64) sb[tid] = bias[tid];

    const int node0 = blockIdx.x * NPB;
    const int lane16 = tid & 15;
    const int grp = tid >> 4;
    const int c4 = lane16 * 4;

    for (int r = 0; r < 2; ++r) {
        const int nl = r * 16 + grp;
        const int node = node0 + nl;
        float4 xv = make_float4(0.f, 0.f, 0.f, 0.f);
        float4 acc = make_float4(0.f, 0.f, 0.f, 0.f);
        if (node < N) {
            xv = *(const float4*)(xin + (size_t)node * 64 + c4);
            const int beg = row_start[node];
            const int end = row_start[node + 1];
            for (int i = beg; i < end; ++i) {
                const int s = col[i];   // same addr across the 16-lane group: broadcast
                const float4 v = *(const float4*)(xin + (size_t)s * 64 + c4);
                acc.x += v.x; acc.y += v.y; acc.z += v.z; acc.w += v.w;
            }
            const float rd = 1.0f / fmaxf((float)(end - beg), 1.0f);
            acc.x *= rd; acc.y *= rd; acc.z *= rd; acc.w *= rd;
        }
        *(float4*)(&sx[nl][c4]) = xv;
        *(float4*)(&sm[nl][c4]) = acc;
    }
    __syncthreads();

    const int n = tid >> 3;
    const int j0 = (tid & 7) * 8;
    float acc[8];
#pragma unroll
    for (int jj = 0; jj < 8; jj++) acc[jj] = sb[j0 + jj];

    for (int k = 0; k < 64; k++) {
        const float xv = sx[n][k];
        const float mv = sm[n][k];
        const float* ws = &sWs[k * 64 + j0];
        const float* wn = &sWn[k * 64 + j0];
#pragma unroll
        for (int jj = 0; jj < 8; jj++) {
            acc[jj] += xv * ws[jj] + mv * wn[jj];
        }
    }

    const int node = node0 + n;
    if (node < N) {
#pragma unroll
        for (int jj = 0; jj < 8; jj++) {
            float v = acc[jj];
            if (do_relu) v = fmaxf(v, 0.f);
            out[(size_t)node * 64 + j0 + jj] = v;
        }
    }
}

extern "C" void kernel_launch(void* const* d_in, const int* in_sizes, int n_in,
                              void* d_out, int out_size, void* d_ws, size_t ws_size,
                              hipStream_t stream) {
    const float* x   = (const float*)d_in[0];
    const int*   ei  = (const int*)d_in[1];
    const float* ws1 = (const float*)d_in[2];
    const float* wn1 = (const float*)d_in[3];
    const float* b1  = (const float*)d_in[4];
    const float* ws2 = (const float*)d_in[5];
    const float* wn2 = (const float*)d_in[6];
    const float* b2  = (const float*)d_in[7];
    const float* ws3 = (const float*)d_in[8];
    const float* wn3 = (const float*)d_in[9];
    const float* b3  = (const float*)d_in[10];

    const int N = in_sizes[0] / 64;   // 100000
    const int E = in_sizes[1] / 2;    // 1600000
    const int* src = ei;
    const int* dst = ei + E;

    float* out = (float*)d_out;       // doubles as h1 temp

    auto align256 = [](size_t v) { return (v + 255) / 256 * 256; };
    char* p = (char*)d_ws;
    int* cnt       = (int*)p; p += align256((size_t)N * 4);        // reused as cursor
    int* row_start = (int*)p; p += align256((size_t)(N + 1) * 4);
    int* bsums     = (int*)p; p += align256(512 * 4);
    int* col       = (int*)p; p += align256((size_t)E * 4);
    float* h2      = (float*)p;                                    // N*64 floats

    const int edge_blocks = (E + 255) / 256;           // 6250
    const int node_blocks = (N + 255) / 256;           // 391
    const int layer_blocks = (N + NPB - 1) / NPB;      // 3125

    // ---- CSR build (per call; ws is re-poisoned each launch) ----
    hipMemsetAsync(cnt, 0, (size_t)N * 4, stream);
    count_kernel<<<edge_blocks, 256, 0, stream>>>(dst, cnt, E);
    scan1_kernel<<<node_blocks, 256, 0, stream>>>(cnt, row_start, bsums, N);
    scan2_kernel<<<1, 512, 0, stream>>>(bsums, node_blocks);
    scan3_kernel<<<node_blocks, 256, 0, stream>>>(row_start, cnt, bsums, N, E);
    fill_kernel<<<edge_blocks, 256, 0, stream>>>(src, dst, cnt, col, E);

    // ---- 3 fused layers ----
    sage_layer_kernel<<<layer_blocks, 256, 0, stream>>>(x,   col, row_start, ws1, wn1, b1, out, N, 1);
    sage_layer_kernel<<<layer_blocks, 256, 0, stream>>>(out, col, row_start, ws2, wn2, b2, h2,  N, 1);
    sage_layer_kernel<<<layer_blocks, 256, 0, stream>>>(h2,  col, row_start, ws3, wn3, b3, out, N, 0);
}

// Round 3
// 570.796 us; speedup vs baseline: 7.7059x; 1.3240x over previous
//
#include <hip/hip_runtime.h>
#include <hip/hip_bf16.h>

#define NPB 32  // nodes per block in update kernel

// ---------- CSR build ----------
__global__ __launch_bounds__(256) void count_kernel(const int* __restrict__ dst,
                                                    int* __restrict__ cnt, int E) {
    int e = blockIdx.x * 256 + threadIdx.x;
    if (e < E) atomicAdd(&cnt[dst[e]], 1);
}

__global__ __launch_bounds__(256) void scan1_kernel(const int* __restrict__ cnt,
                                                    int* __restrict__ excl,
                                                    int* __restrict__ bsums, int N) {
    __shared__ int tmp[256];
    const int tid = threadIdx.x;
    const int g = blockIdx.x * 256 + tid;
    int v = (g < N) ? cnt[g] : 0;
    tmp[tid] = v;
    __syncthreads();
    for (int off = 1; off < 256; off <<= 1) {
        int t = (tid >= off) ? tmp[tid - off] : 0;
        __syncthreads();
        tmp[tid] += t;
        __syncthreads();
    }
    if (g < N) excl[g] = tmp[tid] - v;
    if (tid == 255) bsums[blockIdx.x] = tmp[255];
}

__global__ __launch_bounds__(512) void scan2_kernel(int* bsums, int nb) {
    __shared__ int tmp[512];
    const int tid = threadIdx.x;
    int v = (tid < nb) ? bsums[tid] : 0;
    tmp[tid] = v;
    __syncthreads();
    for (int off = 1; off < 512; off <<= 1) {
        int t = (tid >= off) ? tmp[tid - off] : 0;
        __syncthreads();
        tmp[tid] += t;
        __syncthreads();
    }
    if (tid < nb) bsums[tid] = tmp[tid] - v;  // exclusive
}

__global__ __launch_bounds__(256) void scan3_kernel(int* __restrict__ row_start,
                                                    int* __restrict__ cursor,
                                                    const int* __restrict__ bsums,
                                                    int N, int E) {
    const int g = blockIdx.x * 256 + threadIdx.x;
    if (g < N) {
        int v = row_start[g] + bsums[g >> 8];
        row_start[g] = v;
        cursor[g] = v;
    }
    if (g == 0) row_start[N] = E;
}

__global__ __launch_bounds__(256) void fill_kernel(const int* __restrict__ src,
                                                   const int* __restrict__ dst,
                                                   int* __restrict__ cursor,
                                                   int* __restrict__ col, int E) {
    int e = blockIdx.x * 256 + threadIdx.x;
    if (e >= E) return;
    int slot = atomicAdd(&cursor[dst[e]], 1);
    col[slot] = src[e];
}

// ---------- gather-mean: mean[n] = sum_{e in row n} xin[col[e]] / deg ----------
// 16 lanes per node (4 channels each), 16 nodes/block. No LDS -> full occupancy.
// Edge loop unrolled x4 with independent accumulators -> 16 gathers in flight/wave.
__global__ __launch_bounds__(256) void gather_mean_kernel(
        const float* __restrict__ xin, const int* __restrict__ col,
        const int* __restrict__ row_start, float* __restrict__ mean, int N) {
    const int tid = threadIdx.x;
    const int node = blockIdx.x * 16 + (tid >> 4);
    const int c4 = (tid & 15) * 4;
    if (node >= N) return;
    const int beg = row_start[node];
    const int end = row_start[node + 1];

    float4 a0 = make_float4(0.f, 0.f, 0.f, 0.f);
    float4 a1 = make_float4(0.f, 0.f, 0.f, 0.f);
    float4 a2 = make_float4(0.f, 0.f, 0.f, 0.f);
    float4 a3 = make_float4(0.f, 0.f, 0.f, 0.f);

    int i = beg;
    for (; i + 4 <= end; i += 4) {
        const int s0 = col[i + 0];
        const int s1 = col[i + 1];
        const int s2 = col[i + 2];
        const int s3 = col[i + 3];
        const float4 v0 = *(const float4*)(xin + (size_t)s0 * 64 + c4);
        const float4 v1 = *(const float4*)(xin + (size_t)s1 * 64 + c4);
        const float4 v2 = *(const float4*)(xin + (size_t)s2 * 64 + c4);
        const float4 v3 = *(const float4*)(xin + (size_t)s3 * 64 + c4);
        a0.x += v0.x; a0.y += v0.y; a0.z += v0.z; a0.w += v0.w;
        a1.x += v1.x; a1.y += v1.y; a1.z += v1.z; a1.w += v1.w;
        a2.x += v2.x; a2.y += v2.y; a2.z += v2.z; a2.w += v2.w;
        a3.x += v3.x; a3.y += v3.y; a3.z += v3.z; a3.w += v3.w;
    }
    for (; i < end; ++i) {
        const int s = col[i];
        const float4 v = *(const float4*)(xin + (size_t)s * 64 + c4);
        a0.x += v.x; a0.y += v.y; a0.z += v.z; a0.w += v.w;
    }
    float4 acc;
    acc.x = (a0.x + a1.x) + (a2.x + a3.x);
    acc.y = (a0.y + a1.y) + (a2.y + a3.y);
    acc.z = (a0.z + a1.z) + (a2.z + a3.z);
    acc.w = (a0.w + a1.w) + (a2.w + a3.w);
    const float rd = 1.0f / fmaxf((float)(end - beg), 1.0f);
    acc.x *= rd; acc.y *= rd; acc.z *= rd; acc.w *= rd;
    *(float4*)(mean + (size_t)node * 64 + c4) = acc;
}

// ---------- update: out = xin@Ws + mean@Wn + b (opt relu) ----------
// IN-PLACE SAFE: reads xin/mean ONLY for this block's own nodes (staged to LDS
// before __syncthreads), writes only its own nodes -> out may alias xin or mean.
__global__ __launch_bounds__(256) void update_kernel(const float* __restrict__ xin,
                                                     const float* __restrict__ mean,
                                                     const float* __restrict__ Ws,
                                                     const float* __restrict__ Wn,
                                                     const float* __restrict__ bias,
                                                     float* __restrict__ out,
                                                     int N, int do_relu) {
    __shared__ float sWs[4096];
    __shared__ float sWn[4096];
    __shared__ float sb[64];
    __shared__ float sx[NPB][68];
    __shared__ float sm[NPB][68];

    const int tid = threadIdx.x;
    for (int i = tid; i < 4096; i += 256) {
        sWs[i] = Ws[i];
        sWn[i] = Wn[i];
    }
    if (tid < 64) sb[tid] = bias[tid];

    const int node0 = blockIdx.x * NPB;
    {
        const int nl = tid >> 4;            // 0..15, two rounds
        const int c4 = (tid & 15) * 4;
        for (int r = 0; r < 2; ++r) {
            const int n = r * 16 + nl;
            const int node = node0 + n;
            float4 xv = make_float4(0.f, 0.f, 0.f, 0.f);
            float4 mv = make_float4(0.f, 0.f, 0.f, 0.f);
            if (node < N) {
                xv = *(const float4*)(xin + (size_t)node * 64 + c4);
                mv = *(const float4*)(mean + (size_t)node * 64 + c4);
            }
            *(float4*)(&sx[n][c4]) = xv;
            *(float4*)(&sm[n][c4]) = mv;
        }
    }
    __syncthreads();

    const int n = tid >> 3;
    const int j0 = (tid & 7) * 8;
    float acc[8];
#pragma unroll
    for (int jj = 0; jj < 8; jj++) acc[jj] = sb[j0 + jj];

    for (int k = 0; k < 64; k++) {
        const float xv = sx[n][k];
        const float mv = sm[n][k];
        const float* ws = &sWs[k * 64 + j0];
        const float* wn = &sWn[k * 64 + j0];
#pragma unroll
        for (int jj = 0; jj < 8; jj++) {
            acc[jj] += xv * ws[jj] + mv * wn[jj];
        }
    }

    const int node = node0 + n;
    if (node < N) {
#pragma unroll
        for (int jj = 0; jj < 8; jj++) {
            float v = acc[jj];
            if (do_relu) v = fmaxf(v, 0.f);
            out[(size_t)node * 64 + j0 + jj] = v;
        }
    }
}

extern "C" void kernel_launch(void* const* d_in, const int* in_sizes, int n_in,
                              void* d_out, int out_size, void* d_ws, size_t ws_size,
                              hipStream_t stream) {
    const float* x   = (const float*)d_in[0];
    const int*   ei  = (const int*)d_in[1];
    const float* ws1 = (const float*)d_in[2];
    const float* wn1 = (const float*)d_in[3];
    const float* b1  = (const float*)d_in[4];
    const float* ws2 = (const float*)d_in[5];
    const float* wn2 = (const float*)d_in[6];
    const float* b2  = (const float*)d_in[7];
    const float* ws3 = (const float*)d_in[8];
    const float* wn3 = (const float*)d_in[9];
    const float* b3  = (const float*)d_in[10];

    const int N = in_sizes[0] / 64;   // 100000
    const int E = in_sizes[1] / 2;    // 1600000
    const int* src = ei;
    const int* dst = ei + E;

    float* out = (float*)d_out;

    auto align256 = [](size_t v) { return (v + 255) / 256 * 256; };
    char* p = (char*)d_ws;
    int* cnt       = (int*)p; p += align256((size_t)N * 4);        // reused as cursor
    int* row_start = (int*)p; p += align256((size_t)(N + 1) * 4);
    int* bsums     = (int*)p; p += align256(512 * 4);
    int* col       = (int*)p; p += align256((size_t)E * 4);
    float* hbuf    = (float*)p;                                    // N*64 floats

    const int edge_blocks = (E + 255) / 256;        // 6250
    const int node_blocks = (N + 255) / 256;        // 391
    const int gm_blocks   = (N + 15) / 16;          // 6250
    const int upd_blocks  = (N + NPB - 1) / NPB;    // 3125

    // ---- CSR build ----
    hipMemsetAsync(cnt, 0, (size_t)N * 4, stream);
    count_kernel<<<edge_blocks, 256, 0, stream>>>(dst, cnt, E);
    scan1_kernel<<<node_blocks, 256, 0, stream>>>(cnt, row_start, bsums, N);
    scan2_kernel<<<1, 512, 0, stream>>>(bsums, node_blocks);
    scan3_kernel<<<node_blocks, 256, 0, stream>>>(row_start, cnt, bsums, N, E);
    fill_kernel<<<edge_blocks, 256, 0, stream>>>(src, dst, cnt, col, E);

    // ---- layer 1: x -> hbuf(h1) ----
    gather_mean_kernel<<<gm_blocks, 256, 0, stream>>>(x, col, row_start, hbuf, N);
    update_kernel<<<upd_blocks, 256, 0, stream>>>(x, hbuf, ws1, wn1, b1, hbuf, N, 1);
    // ---- layer 2: hbuf(h1) -> hbuf(h2), mean2 staged in d_out ----
    gather_mean_kernel<<<gm_blocks, 256, 0, stream>>>(hbuf, col, row_start, out, N);
    update_kernel<<<upd_blocks, 256, 0, stream>>>(hbuf, out, ws2, wn2, b2, hbuf, N, 1);
    // ---- layer 3: hbuf(h2) -> d_out, mean3 staged in d_out (in-place) ----
    gather_mean_kernel<<<gm_blocks, 256, 0, stream>>>(hbuf, col, row_start, out, N);
    update_kernel<<<upd_blocks, 256, 0, stream>>>(hbuf, out, ws3, wn3, b3, out, N, 0);
}

// Round 4
// 488.105 us; speedup vs baseline: 9.0114x; 1.1694x over previous
//
#include <hip/hip_runtime.h>
#include <hip/hip_bf16.h>

#define PB   64   // partition blocks (big stripes -> long per-segment runs)
#define NPB  32   // nodes per block in update kernel

// ============ CSR build: radix partition by dst>>8 (segment-local writes) ============

// K1: per-block histogram of dst buckets. counts layout: [bucket][block] (bucket-major).
__global__ __launch_bounds__(256) void part_hist(const int* __restrict__ dst,
                                                 int* __restrict__ counts,
                                                 int E, int NB) {
    __shared__ int h[512];
    const int tid = threadIdx.x;
    for (int i = tid; i < NB; i += 256) h[i] = 0;
    __syncthreads();
    const int per = (E + PB - 1) / PB;
    const int s = blockIdx.x * per;
    const int e = min(E, s + per);
    for (int i = s + tid; i < e; i += 256) atomicAdd(&h[dst[i] >> 8], 1);
    __syncthreads();
    for (int i = tid; i < NB; i += 256) counts[i * PB + blockIdx.x] = h[i];
}

// K2: single block. bucket totals -> exclusive scan -> bucket_base;
// per-(bucket,block) segment bases.
__global__ __launch_bounds__(512) void part_scan(const int* __restrict__ counts,
                                                 int* __restrict__ bucket_base,
                                                 int* __restrict__ seg_base,
                                                 int NB, int E) {
    __shared__ int tmp[512];
    const int tid = threadIdx.x;
    int tot = 0;
    if (tid < NB)
        for (int k = 0; k < PB; ++k) tot += counts[tid * PB + k];
    tmp[tid] = tot;
    __syncthreads();
    for (int off = 1; off < 512; off <<= 1) {
        int t = (tid >= off) ? tmp[tid - off] : 0;
        __syncthreads();
        tmp[tid] += t;
        __syncthreads();
    }
    const int excl = tmp[tid] - tot;
    if (tid < NB) {
        bucket_base[tid] = excl;
        int run = excl;
        for (int k = 0; k < PB; ++k) {
            seg_base[tid * PB + k] = run;
            run += counts[tid * PB + k];
        }
    }
    if (tid == 0) bucket_base[NB] = E;
}

// K3: partition pass. Each block writes its bucket-b edges sequentially into its
// private segment -> full-line writebacks (no 16x amplification).
// Packed entry: src (20 bits) | dst_local (8 bits) << 20.
__global__ __launch_bounds__(256) void part_scatter(const int* __restrict__ src,
                                                    const int* __restrict__ dst,
                                                    const int* __restrict__ seg_base,
                                                    int* __restrict__ pairs,
                                                    int E, int NB) {
    __shared__ int cur[512];
    const int tid = threadIdx.x;
    for (int i = tid; i < NB; i += 256) cur[i] = seg_base[i * PB + blockIdx.x];
    __syncthreads();
    const int per = (E + PB - 1) / PB;
    const int s = blockIdx.x * per;
    const int e = min(E, s + per);
    for (int i = s + tid; i < e; i += 256) {
        const int d = dst[i];
        const int b = d >> 8;
        const int slot = atomicAdd(&cur[b], 1);
        pairs[slot] = src[i] | ((d & 255) << 20);
    }
}

// K4: one block per bucket (256 nodes). Local histogram + scan -> row_start;
// scatter col within the bucket's own ~16KB region (single XCD -> L2-local).
__global__ __launch_bounds__(256) void csr_finalize(const int* __restrict__ pairs,
                                                    const int* __restrict__ bucket_base,
                                                    int* __restrict__ row_start,
                                                    int* __restrict__ col,
                                                    int N, int E) {
    __shared__ int h[256];
    __shared__ int tmp[256];
    __shared__ int cur[256];
    const int tid = threadIdx.x;
    const int b = blockIdx.x;
    const int node0 = b << 8;
    const int pbeg = bucket_base[b];
    const int pend = bucket_base[b + 1];
    h[tid] = 0;
    __syncthreads();
    for (int i = pbeg + tid; i < pend; i += 256)
        atomicAdd(&h[(pairs[i] >> 20) & 255], 1);
    __syncthreads();
    const int v = h[tid];
    tmp[tid] = v;
    __syncthreads();
    for (int off = 1; off < 256; off <<= 1) {
        int t = (tid >= off) ? tmp[tid - off] : 0;
        __syncthreads();
        tmp[tid] += t;
        __syncthreads();
    }
    const int excl = tmp[tid] - v;
    cur[tid] = pbeg + excl;
    if (node0 + tid < N) row_start[node0 + tid] = pbeg + excl;
    if (b == 0 && tid == 0) row_start[N] = E;
    __syncthreads();
    for (int i = pbeg + tid; i < pend; i += 256) {
        const int p = pairs[i];
        const int slot = atomicAdd(&cur[(p >> 20) & 255], 1);
        col[slot] = p & 0xFFFFF;
    }
}

// ============ gather-mean: mean[n] = sum_{e in row n} xin[col[e]] / deg ============
// 16 lanes per node (4 channels each), 16 nodes/block, no LDS, edge loop x4 unroll.
__global__ __launch_bounds__(256) void gather_mean_kernel(
        const float* __restrict__ xin, const int* __restrict__ col,
        const int* __restrict__ row_start, float* __restrict__ mean, int N) {
    const int tid = threadIdx.x;
    const int node = blockIdx.x * 16 + (tid >> 4);
    const int c4 = (tid & 15) * 4;
    if (node >= N) return;
    const int beg = row_start[node];
    const int end = row_start[node + 1];

    float4 a0 = make_float4(0.f, 0.f, 0.f, 0.f);
    float4 a1 = make_float4(0.f, 0.f, 0.f, 0.f);
    float4 a2 = make_float4(0.f, 0.f, 0.f, 0.f);
    float4 a3 = make_float4(0.f, 0.f, 0.f, 0.f);

    int i = beg;
    for (; i + 4 <= end; i += 4) {
        const int s0 = col[i + 0];
        const int s1 = col[i + 1];
        const int s2 = col[i + 2];
        const int s3 = col[i + 3];
        const float4 v0 = *(const float4*)(xin + (size_t)s0 * 64 + c4);
        const float4 v1 = *(const float4*)(xin + (size_t)s1 * 64 + c4);
        const float4 v2 = *(const float4*)(xin + (size_t)s2 * 64 + c4);
        const float4 v3 = *(const float4*)(xin + (size_t)s3 * 64 + c4);
        a0.x += v0.x; a0.y += v0.y; a0.z += v0.z; a0.w += v0.w;
        a1.x += v1.x; a1.y += v1.y; a1.z += v1.z; a1.w += v1.w;
        a2.x += v2.x; a2.y += v2.y; a2.z += v2.z; a2.w += v2.w;
        a3.x += v3.x; a3.y += v3.y; a3.z += v3.z; a3.w += v3.w;
    }
    for (; i < end; ++i) {
        const int s = col[i];
        const float4 v = *(const float4*)(xin + (size_t)s * 64 + c4);
        a0.x += v.x; a0.y += v.y; a0.z += v.z; a0.w += v.w;
    }
    float4 acc;
    acc.x = (a0.x + a1.x) + (a2.x + a3.x);
    acc.y = (a0.y + a1.y) + (a2.y + a3.y);
    acc.z = (a0.z + a1.z) + (a2.z + a3.z);
    acc.w = (a0.w + a1.w) + (a2.w + a3.w);
    const float rd = 1.0f / fmaxf((float)(end - beg), 1.0f);
    acc.x *= rd; acc.y *= rd; acc.z *= rd; acc.w *= rd;
    *(float4*)(mean + (size_t)node * 64 + c4) = acc;
}

// ============ update: out = xin@Ws + mean@Wn + b (opt relu), in-place safe ============
__global__ __launch_bounds__(256) void update_kernel(const float* __restrict__ xin,
                                                     const float* __restrict__ mean,
                                                     const float* __restrict__ Ws,
                                                     const float* __restrict__ Wn,
                                                     const float* __restrict__ bias,
                                                     float* __restrict__ out,
                                                     int N, int do_relu) {
    __shared__ float sWs[4096];
    __shared__ float sWn[4096];
    __shared__ float sb[64];
    __shared__ float sx[NPB][68];
    __shared__ float sm[NPB][68];

    const int tid = threadIdx.x;
    for (int i = tid; i < 4096; i += 256) {
        sWs[i] = Ws[i];
        sWn[i] = Wn[i];
    }
    if (tid < 64) sb[tid] = bias[tid];

    const int node0 = blockIdx.x * NPB;
    {
        const int nl = tid >> 4;
        const int c4 = (tid & 15) * 4;
        for (int r = 0; r < 2; ++r) {
            const int n = r * 16 + nl;
            const int node = node0 + n;
            float4 xv = make_float4(0.f, 0.f, 0.f, 0.f);
            float4 mv = make_float4(0.f, 0.f, 0.f, 0.f);
            if (node < N) {
                xv = *(const float4*)(xin + (size_t)node * 64 + c4);
                mv = *(const float4*)(mean + (size_t)node * 64 + c4);
            }
            *(float4*)(&sx[n][c4]) = xv;
            *(float4*)(&sm[n][c4]) = mv;
        }
    }
    __syncthreads();

    const int n = tid >> 3;
    const int j0 = (tid & 7) * 8;
    float acc[8];
#pragma unroll
    for (int jj = 0; jj < 8; jj++) acc[jj] = sb[j0 + jj];

    for (int k = 0; k < 64; k++) {
        const float xv = sx[n][k];
        const float mv = sm[n][k];
        const float* ws = &sWs[k * 64 + j0];
        const float* wn = &sWn[k * 64 + j0];
#pragma unroll
        for (int jj = 0; jj < 8; jj++) {
            acc[jj] += xv * ws[jj] + mv * wn[jj];
        }
    }

    const int node = node0 + n;
    if (node < N) {
#pragma unroll
        for (int jj = 0; jj < 8; jj++) {
            float v = acc[jj];
            if (do_relu) v = fmaxf(v, 0.f);
            out[(size_t)node * 64 + j0 + jj] = v;
        }
    }
}

extern "C" void kernel_launch(void* const* d_in, const int* in_sizes, int n_in,
                              void* d_out, int out_size, void* d_ws, size_t ws_size,
                              hipStream_t stream) {
    const float* x   = (const float*)d_in[0];
    const int*   ei  = (const int*)d_in[1];
    const float* ws1 = (const float*)d_in[2];
    const float* wn1 = (const float*)d_in[3];
    const float* b1  = (const float*)d_in[4];
    const float* ws2 = (const float*)d_in[5];
    const float* wn2 = (const float*)d_in[6];
    const float* b2  = (const float*)d_in[7];
    const float* ws3 = (const float*)d_in[8];
    const float* wn3 = (const float*)d_in[9];
    const float* b3  = (const float*)d_in[10];

    const int N = in_sizes[0] / 64;   // 100000
    const int E = in_sizes[1] / 2;    // 1600000
    const int* src = ei;
    const int* dst = ei + E;
    const int NB = (N + 255) >> 8;    // 391 buckets (<= 512)

    float* out = (float*)d_out;

    auto align256 = [](size_t v) { return (v + 255) / 256 * 256; };
    char* p = (char*)d_ws;
    int* counts      = (int*)p; p += align256((size_t)NB * PB * 4);
    int* bucket_base = (int*)p; p += align256((size_t)(NB + 1) * 4);
    int* seg_base    = (int*)p; p += align256((size_t)NB * PB * 4);
    int* row_start   = (int*)p; p += align256((size_t)(N + 1) * 4);
    int* pairs       = (int*)p; p += align256((size_t)E * 4);
    int* col         = (int*)p; p += align256((size_t)E * 4);
    float* hbuf      = (float*)p;     // N*64 floats

    const int gm_blocks  = (N + 15) / 16;         // 6250
    const int upd_blocks = (N + NPB - 1) / NPB;   // 3125

    // ---- CSR build (partitioned, segment-local writes) ----
    part_hist   <<<PB, 256, 0, stream>>>(dst, counts, E, NB);
    part_scan   <<<1, 512, 0, stream>>>(counts, bucket_base, seg_base, NB, E);
    part_scatter<<<PB, 256, 0, stream>>>(src, dst, seg_base, pairs, E, NB);
    csr_finalize<<<NB, 256, 0, stream>>>(pairs, bucket_base, row_start, col, N, E);

    // ---- layer 1: x -> hbuf(h1) ----
    gather_mean_kernel<<<gm_blocks, 256, 0, stream>>>(x, col, row_start, hbuf, N);
    update_kernel<<<upd_blocks, 256, 0, stream>>>(x, hbuf, ws1, wn1, b1, hbuf, N, 1);
    // ---- layer 2: hbuf(h1) -> hbuf(h2), mean staged in d_out ----
    gather_mean_kernel<<<gm_blocks, 256, 0, stream>>>(hbuf, col, row_start, out, N);
    update_kernel<<<upd_blocks, 256, 0, stream>>>(hbuf, out, ws2, wn2, b2, hbuf, N, 1);
    // ---- layer 3: hbuf(h2) -> d_out (mean staged in d_out, in-place update) ----
    gather_mean_kernel<<<gm_blocks, 256, 0, stream>>>(hbuf, col, row_start, out, N);
    update_kernel<<<upd_blocks, 256, 0, stream>>>(hbuf, out, ws3, wn3, b3, out, N, 0);
}

// Round 5
// 424.261 us; speedup vs baseline: 10.3675x; 1.1505x over previous
//
#include <hip/hip_runtime.h>
#include <hip/hip_bf16.h>

#define PB   512  // partition blocks: 2 blocks/CU -> full-chip parallelism
#define NPB  32   // nodes per block in update kernel

// ============ CSR build: radix partition by dst>>8 (segment-local writes) ============

// K1: per-block histogram of dst buckets. counts layout: [bucket][block] (bucket-major).
__global__ __launch_bounds__(256) void part_hist(const int* __restrict__ dst,
                                                 int* __restrict__ counts,
                                                 int E, int NB) {
    __shared__ int h[512];
    const int tid = threadIdx.x;
    for (int i = tid; i < NB; i += 256) h[i] = 0;
    __syncthreads();
    const int per = (E + PB - 1) / PB;
    const int s = blockIdx.x * per;
    const int e = min(E, s + per);
    for (int i = s + tid; i < e; i += 256) atomicAdd(&h[dst[i] >> 8], 1);
    __syncthreads();
    for (int i = tid; i < NB; i += 256) counts[i * PB + blockIdx.x] = h[i];
}

// K2a/b/c: hierarchical exclusive scan of counts[M] (M = NB*PB, bucket-major)
// -> seg_base[M]; bucket_base[b] = seg_base[b*PB].
__global__ __launch_bounds__(256) void scanA(const int* __restrict__ in,
                                             int* __restrict__ excl,
                                             int* __restrict__ bsums, int M) {
    __shared__ int tmp[256];
    const int tid = threadIdx.x;
    const int g = blockIdx.x * 256 + tid;
    int v = (g < M) ? in[g] : 0;
    tmp[tid] = v;
    __syncthreads();
    for (int off = 1; off < 256; off <<= 1) {
        int t = (tid >= off) ? tmp[tid - off] : 0;
        __syncthreads();
        tmp[tid] += t;
        __syncthreads();
    }
    if (g < M) excl[g] = tmp[tid] - v;
    if (tid == 255) bsums[blockIdx.x] = tmp[255];
}

__global__ __launch_bounds__(1024) void scanB(int* bsums, int nb) {
    __shared__ int tmp[1024];
    const int tid = threadIdx.x;
    int v = (tid < nb) ? bsums[tid] : 0;
    tmp[tid] = v;
    __syncthreads();
    for (int off = 1; off < 1024; off <<= 1) {
        int t = (tid >= off) ? tmp[tid - off] : 0;
        __syncthreads();
        tmp[tid] += t;
        __syncthreads();
    }
    if (tid < nb) bsums[tid] = tmp[tid] - v;  // exclusive
}

__global__ __launch_bounds__(256) void scanC(int* __restrict__ seg_base,
                                             const int* __restrict__ bsums,
                                             int* __restrict__ bucket_base,
                                             int M, int NB, int E) {
    const int g = blockIdx.x * 256 + threadIdx.x;
    if (g < M) {
        const int v = seg_base[g] + bsums[g >> 8];
        seg_base[g] = v;
        if ((g & (PB - 1)) == 0) bucket_base[g / PB] = v;
    }
    if (g == 0) bucket_base[NB] = E;
}

// K3: partition pass. Each block writes its bucket-b edges sequentially into its
// private segment. Packed entry: src (20 bits) | dst_local (8 bits) << 20.
__global__ __launch_bounds__(256) void part_scatter(const int* __restrict__ src,
                                                    const int* __restrict__ dst,
                                                    const int* __restrict__ seg_base,
                                                    int* __restrict__ pairs,
                                                    int E, int NB) {
    __shared__ int cur[512];
    const int tid = threadIdx.x;
    for (int i = tid; i < NB; i += 256) cur[i] = seg_base[i * PB + blockIdx.x];
    __syncthreads();
    const int per = (E + PB - 1) / PB;
    const int s = blockIdx.x * per;
    const int e = min(E, s + per);
    for (int i = s + tid; i < e; i += 256) {
        const int d = dst[i];
        const int b = d >> 8;
        const int slot = atomicAdd(&cur[b], 1);
        pairs[slot] = src[i] | ((d & 255) << 20);
    }
}

// K4: one block per bucket (256 nodes). Local histogram + scan -> row_start;
// scatter col within the bucket's own ~16KB region.
__global__ __launch_bounds__(256) void csr_finalize(const int* __restrict__ pairs,
                                                    const int* __restrict__ bucket_base,
                                                    int* __restrict__ row_start,
                                                    int* __restrict__ col,
                                                    int N, int E) {
    __shared__ int h[256];
    __shared__ int tmp[256];
    __shared__ int cur[256];
    const int tid = threadIdx.x;
    const int b = blockIdx.x;
    const int node0 = b << 8;
    const int pbeg = bucket_base[b];
    const int pend = bucket_base[b + 1];
    h[tid] = 0;
    __syncthreads();
    for (int i = pbeg + tid; i < pend; i += 256)
        atomicAdd(&h[(pairs[i] >> 20) & 255], 1);
    __syncthreads();
    const int v = h[tid];
    tmp[tid] = v;
    __syncthreads();
    for (int off = 1; off < 256; off <<= 1) {
        int t = (tid >= off) ? tmp[tid - off] : 0;
        __syncthreads();
        tmp[tid] += t;
        __syncthreads();
    }
    const int excl = tmp[tid] - v;
    cur[tid] = pbeg + excl;
    if (node0 + tid < N) row_start[node0 + tid] = pbeg + excl;
    if (b == 0 && tid == 0) row_start[N] = E;
    __syncthreads();
    for (int i = pbeg + tid; i < pend; i += 256) {
        const int p = pairs[i];
        const int slot = atomicAdd(&cur[(p >> 20) & 255], 1);
        col[slot] = p & 0xFFFFF;
    }
}

// ============ gather-mean: mean[n] = sum_{e in row n} xin[col[e]] / deg ============
// 16 lanes per node (4 channels each), 16 nodes/block, no LDS, edge loop x4 unroll.
__global__ __launch_bounds__(256) void gather_mean_kernel(
        const float* __restrict__ xin, const int* __restrict__ col,
        const int* __restrict__ row_start, float* __restrict__ mean, int N) {
    const int tid = threadIdx.x;
    const int node = blockIdx.x * 16 + (tid >> 4);
    const int c4 = (tid & 15) * 4;
    if (node >= N) return;
    const int beg = row_start[node];
    const int end = row_start[node + 1];

    float4 a0 = make_float4(0.f, 0.f, 0.f, 0.f);
    float4 a1 = make_float4(0.f, 0.f, 0.f, 0.f);
    float4 a2 = make_float4(0.f, 0.f, 0.f, 0.f);
    float4 a3 = make_float4(0.f, 0.f, 0.f, 0.f);

    int i = beg;
    for (; i + 4 <= end; i += 4) {
        const int s0 = col[i + 0];
        const int s1 = col[i + 1];
        const int s2 = col[i + 2];
        const int s3 = col[i + 3];
        const float4 v0 = *(const float4*)(xin + (size_t)s0 * 64 + c4);
        const float4 v1 = *(const float4*)(xin + (size_t)s1 * 64 + c4);
        const float4 v2 = *(const float4*)(xin + (size_t)s2 * 64 + c4);
        const float4 v3 = *(const float4*)(xin + (size_t)s3 * 64 + c4);
        a0.x += v0.x; a0.y += v0.y; a0.z += v0.z; a0.w += v0.w;
        a1.x += v1.x; a1.y += v1.y; a1.z += v1.z; a1.w += v1.w;
        a2.x += v2.x; a2.y += v2.y; a2.z += v2.z; a2.w += v2.w;
        a3.x += v3.x; a3.y += v3.y; a3.z += v3.z; a3.w += v3.w;
    }
    for (; i < end; ++i) {
        const int s = col[i];
        const float4 v = *(const float4*)(xin + (size_t)s * 64 + c4);
        a0.x += v.x; a0.y += v.y; a0.z += v.z; a0.w += v.w;
    }
    float4 acc;
    acc.x = (a0.x + a1.x) + (a2.x + a3.x);
    acc.y = (a0.y + a1.y) + (a2.y + a3.y);
    acc.z = (a0.z + a1.z) + (a2.z + a3.z);
    acc.w = (a0.w + a1.w) + (a2.w + a3.w);
    const float rd = 1.0f / fmaxf((float)(end - beg), 1.0f);
    acc.x *= rd; acc.y *= rd; acc.z *= rd; acc.w *= rd;
    *(float4*)(mean + (size_t)node * 64 + c4) = acc;
}

// ============ update: out = xin@Ws + mean@Wn + b (opt relu), in-place safe ============
__global__ __launch_bounds__(256) void update_kernel(const float* __restrict__ xin,
                                                     const float* __restrict__ mean,
                                                     const float* __restrict__ Ws,
                                                     const float* __restrict__ Wn,
                                                     const float* __restrict__ bias,
                                                     float* __restrict__ out,
                                                     int N, int do_relu) {
    __shared__ float sWs[4096];
    __shared__ float sWn[4096];
    __shared__ float sb[64];
    __shared__ float sx[NPB][68];
    __shared__ float sm[NPB][68];

    const int tid = threadIdx.x;
    for (int i = tid; i < 4096; i += 256) {
        sWs[i] = Ws[i];
        sWn[i] = Wn[i];
    }
    if (tid < 64) sb[tid] = bias[tid];

    const int node0 = blockIdx.x * NPB;
    {
        const int nl = tid >> 4;
        const int c4 = (tid & 15) * 4;
        for (int r = 0; r < 2; ++r) {
            const int n = r * 16 + nl;
            const int node = node0 + n;
            float4 xv = make_float4(0.f, 0.f, 0.f, 0.f);
            float4 mv = make_float4(0.f, 0.f, 0.f, 0.f);
            if (node < N) {
                xv = *(const float4*)(xin + (size_t)node * 64 + c4);
                mv = *(const float4*)(mean + (size_t)node * 64 + c4);
            }
            *(float4*)(&sx[n][c4]) = xv;
            *(float4*)(&sm[n][c4]) = mv;
        }
    }
    __syncthreads();

    const int n = tid >> 3;
    const int j0 = (tid & 7) * 8;
    float acc[8];
#pragma unroll
    for (int jj = 0; jj < 8; jj++) acc[jj] = sb[j0 + jj];

    for (int k = 0; k < 64; k++) {
        const float xv = sx[n][k];
        const float mv = sm[n][k];
        const float* ws = &sWs[k * 64 + j0];
        const float* wn = &sWn[k * 64 + j0];
#pragma unroll
        for (int jj = 0; jj < 8; jj++) {
            acc[jj] += xv * ws[jj] + mv * wn[jj];
        }
    }

    const int node = node0 + n;
    if (node < N) {
#pragma unroll
        for (int jj = 0; jj < 8; jj++) {
            float v = acc[jj];
            if (do_relu) v = fmaxf(v, 0.f);
            out[(size_t)node * 64 + j0 + jj] = v;
        }
    }
}

extern "C" void kernel_launch(void* const* d_in, const int* in_sizes, int n_in,
                              void* d_out, int out_size, void* d_ws, size_t ws_size,
                              hipStream_t stream) {
    const float* x   = (const float*)d_in[0];
    const int*   ei  = (const int*)d_in[1];
    const float* ws1 = (const float*)d_in[2];
    const float* wn1 = (const float*)d_in[3];
    const float* b1  = (const float*)d_in[4];
    const float* ws2 = (const float*)d_in[5];
    const float* wn2 = (const float*)d_in[6];
    const float* b2  = (const float*)d_in[7];
    const float* ws3 = (const float*)d_in[8];
    const float* wn3 = (const float*)d_in[9];
    const float* b3  = (const float*)d_in[10];

    const int N = in_sizes[0] / 64;   // 100000
    const int E = in_sizes[1] / 2;    // 1600000
    const int* src = ei;
    const int* dst = ei + E;
    const int NB = (N + 255) >> 8;    // 391 buckets
    const int M  = NB * PB;           // flat counts/seg_base length

    float* out = (float*)d_out;

    auto align256 = [](size_t v) { return (v + 255) / 256 * 256; };
    char* p = (char*)d_ws;
    int* counts      = (int*)p; p += align256((size_t)M * 4);
    int* seg_base    = (int*)p; p += align256((size_t)M * 4);
    int* bsums       = (int*)p; p += align256(1024 * 4);
    int* bucket_base = (int*)p; p += align256((size_t)(NB + 1) * 4);
    int* row_start   = (int*)p; p += align256((size_t)(N + 1) * 4);
    int* pairs       = (int*)p; p += align256((size_t)E * 4);
    int* col         = (int*)p; p += align256((size_t)E * 4);
    float* hbuf      = (float*)p;     // N*64 floats

    const int scan_blocks = (M + 255) / 256;      // 782 (<= 1024 for scanB)
    const int gm_blocks   = (N + 15) / 16;        // 6250
    const int upd_blocks  = (N + NPB - 1) / NPB;  // 3125

    // ---- CSR build (partitioned, segment-local writes, full-chip parallel) ----
    part_hist   <<<PB, 256, 0, stream>>>(dst, counts, E, NB);
    scanA       <<<scan_blocks, 256, 0, stream>>>(counts, seg_base, bsums, M);
    scanB       <<<1, 1024, 0, stream>>>(bsums, scan_blocks);
    scanC       <<<scan_blocks, 256, 0, stream>>>(seg_base, bsums, bucket_base, M, NB, E);
    part_scatter<<<PB, 256, 0, stream>>>(src, dst, seg_base, pairs, E, NB);
    csr_finalize<<<NB, 256, 0, stream>>>(pairs, bucket_base, row_start, col, N, E);

    // ---- layer 1: x -> hbuf(h1) ----
    gather_mean_kernel<<<gm_blocks, 256, 0, stream>>>(x, col, row_start, hbuf, N);
    update_kernel<<<upd_blocks, 256, 0, stream>>>(x, hbuf, ws1, wn1, b1, hbuf, N, 1);
    // ---- layer 2: hbuf(h1) -> hbuf(h2), mean staged in d_out ----
    gather_mean_kernel<<<gm_blocks, 256, 0, stream>>>(hbuf, col, row_start, out, N);
    update_kernel<<<upd_blocks, 256, 0, stream>>>(hbuf, out, ws2, wn2, b2, hbuf, N, 1);
    // ---- layer 3: hbuf(h2) -> d_out (mean staged in d_out, in-place update) ----
    gather_mean_kernel<<<gm_blocks, 256, 0, stream>>>(hbuf, col, row_start, out, N);
    update_kernel<<<upd_blocks, 256, 0, stream>>>(hbuf, out, ws3, wn3, b3, out, N, 0);
}

// Round 6
// 376.052 us; speedup vs baseline: 11.6966x; 1.1282x over previous
//
#include <hip/hip_runtime.h>
#include <hip/hip_bf16.h>

#define PB   512  // partition blocks: 2 blocks/CU -> full-chip parallelism
#define NPB  32   // nodes per block in update kernel

__device__ __forceinline__ unsigned short f2bf(float f) {  // RNE f32->bf16
    unsigned u = __float_as_uint(f);
    u += 0x7FFFu + ((u >> 16) & 1u);
    return (unsigned short)(u >> 16);
}

// ============ CSR build: radix partition by dst>>8 (segment-local writes) ============

__global__ __launch_bounds__(256) void part_hist(const int* __restrict__ dst,
                                                 int* __restrict__ counts,
                                                 int E, int NB) {
    __shared__ int h[512];
    const int tid = threadIdx.x;
    for (int i = tid; i < NB; i += 256) h[i] = 0;
    __syncthreads();
    const int per = (E + PB - 1) / PB;
    const int s = blockIdx.x * per;
    const int e = min(E, s + per);
    for (int i = s + tid; i < e; i += 256) atomicAdd(&h[dst[i] >> 8], 1);
    __syncthreads();
    for (int i = tid; i < NB; i += 256) counts[i * PB + blockIdx.x] = h[i];
}

__global__ __launch_bounds__(256) void scanA(const int* __restrict__ in,
                                             int* __restrict__ excl,
                                             int* __restrict__ bsums, int M) {
    __shared__ int tmp[256];
    const int tid = threadIdx.x;
    const int g = blockIdx.x * 256 + tid;
    int v = (g < M) ? in[g] : 0;
    tmp[tid] = v;
    __syncthreads();
    for (int off = 1; off < 256; off <<= 1) {
        int t = (tid >= off) ? tmp[tid - off] : 0;
        __syncthreads();
        tmp[tid] += t;
        __syncthreads();
    }
    if (g < M) excl[g] = tmp[tid] - v;
    if (tid == 255) bsums[blockIdx.x] = tmp[255];
}

__global__ __launch_bounds__(1024) void scanB(int* bsums, int nb) {
    __shared__ int tmp[1024];
    const int tid = threadIdx.x;
    int v = (tid < nb) ? bsums[tid] : 0;
    tmp[tid] = v;
    __syncthreads();
    for (int off = 1; off < 1024; off <<= 1) {
        int t = (tid >= off) ? tmp[tid - off] : 0;
        __syncthreads();
        tmp[tid] += t;
        __syncthreads();
    }
    if (tid < nb) bsums[tid] = tmp[tid] - v;  // exclusive
}

__global__ __launch_bounds__(256) void scanC(int* __restrict__ seg_base,
                                             const int* __restrict__ bsums,
                                             int* __restrict__ bucket_base,
                                             int M, int NB, int E) {
    const int g = blockIdx.x * 256 + threadIdx.x;
    if (g < M) {
        const int v = seg_base[g] + bsums[g >> 8];
        seg_base[g] = v;
        if ((g & (PB - 1)) == 0) bucket_base[g / PB] = v;
    }
    if (g == 0) bucket_base[NB] = E;
}

__global__ __launch_bounds__(256) void part_scatter(const int* __restrict__ src,
                                                    const int* __restrict__ dst,
                                                    const int* __restrict__ seg_base,
                                                    int* __restrict__ pairs,
                                                    int E, int NB) {
    __shared__ int cur[512];
    const int tid = threadIdx.x;
    for (int i = tid; i < NB; i += 256) cur[i] = seg_base[i * PB + blockIdx.x];
    __syncthreads();
    const int per = (E + PB - 1) / PB;
    const int s = blockIdx.x * per;
    const int e = min(E, s + per);
    for (int i = s + tid; i < e; i += 256) {
        const int d = dst[i];
        const int b = d >> 8;
        const int slot = atomicAdd(&cur[b], 1);
        pairs[slot] = src[i] | ((d & 255) << 20);
    }
}

__global__ __launch_bounds__(256) void csr_finalize(const int* __restrict__ pairs,
                                                    const int* __restrict__ bucket_base,
                                                    int* __restrict__ row_start,
                                                    int* __restrict__ col,
                                                    int N, int E) {
    __shared__ int h[256];
    __shared__ int tmp[256];
    __shared__ int cur[256];
    const int tid = threadIdx.x;
    const int b = blockIdx.x;
    const int node0 = b << 8;
    const int pbeg = bucket_base[b];
    const int pend = bucket_base[b + 1];
    h[tid] = 0;
    __syncthreads();
    for (int i = pbeg + tid; i < pend; i += 256)
        atomicAdd(&h[(pairs[i] >> 20) & 255], 1);
    __syncthreads();
    const int v = h[tid];
    tmp[tid] = v;
    __syncthreads();
    for (int off = 1; off < 256; off <<= 1) {
        int t = (tid >= off) ? tmp[tid - off] : 0;
        __syncthreads();
        tmp[tid] += t;
        __syncthreads();
    }
    const int excl = tmp[tid] - v;
    cur[tid] = pbeg + excl;
    if (node0 + tid < N) row_start[node0 + tid] = pbeg + excl;
    if (b == 0 && tid == 0) row_start[N] = E;
    __syncthreads();
    for (int i = pbeg + tid; i < pend; i += 256) {
        const int p = pairs[i];
        const int slot = atomicAdd(&cur[(p >> 20) & 255], 1);
        col[slot] = p & 0xFFFFF;
    }
}

// ============ f32 -> bf16 shadow copy (RNE), 8 elems/thread ============
__global__ __launch_bounds__(256) void to_bf16_kernel(const float* __restrict__ in,
                                                      unsigned short* __restrict__ out,
                                                      int n8) {
    const int g = blockIdx.x * 256 + threadIdx.x;
    if (g >= n8) return;
    const float4 v0 = *(const float4*)(in + (size_t)g * 8);
    const float4 v1 = *(const float4*)(in + (size_t)g * 8 + 4);
    uint4 o;
    o.x = (unsigned)f2bf(v0.x) | ((unsigned)f2bf(v0.y) << 16);
    o.y = (unsigned)f2bf(v0.z) | ((unsigned)f2bf(v0.w) << 16);
    o.z = (unsigned)f2bf(v1.x) | ((unsigned)f2bf(v1.y) << 16);
    o.w = (unsigned)f2bf(v1.z) | ((unsigned)f2bf(v1.w) << 16);
    *(uint4*)(out + (size_t)g * 8) = o;
}

// ============ gather-mean over bf16 features ============
// 8 lanes per node (8 bf16 channels each, 16B loads), 32 nodes/block,
// edge loop x4 unroll into two f32 accumulator banks.
#define ACC8(A, V)                                                    \
    A##0 += __uint_as_float((V).x << 16);                             \
    A##1 += __uint_as_float((V).x & 0xFFFF0000u);                     \
    A##2 += __uint_as_float((V).y << 16);                             \
    A##3 += __uint_as_float((V).y & 0xFFFF0000u);                     \
    A##4 += __uint_as_float((V).z << 16);                             \
    A##5 += __uint_as_float((V).z & 0xFFFF0000u);                     \
    A##6 += __uint_as_float((V).w << 16);                             \
    A##7 += __uint_as_float((V).w & 0xFFFF0000u);

__global__ __launch_bounds__(256) void gather_mean_kernel(
        const unsigned short* __restrict__ xb, const int* __restrict__ col,
        const int* __restrict__ row_start, float* __restrict__ mean, int N) {
    const int tid = threadIdx.x;
    const int node = blockIdx.x * 32 + (tid >> 3);
    const int c8 = (tid & 7) * 8;
    if (node >= N) return;
    const int beg = row_start[node];
    const int end = row_start[node + 1];

    float a0 = 0.f, a1 = 0.f, a2 = 0.f, a3 = 0.f, a4 = 0.f, a5 = 0.f, a6 = 0.f, a7 = 0.f;
    float b0 = 0.f, b1 = 0.f, b2 = 0.f, b3 = 0.f, b4 = 0.f, b5 = 0.f, b6 = 0.f, b7 = 0.f;

    int i = beg;
    for (; i + 4 <= end; i += 4) {
        const int s0 = col[i + 0];
        const int s1 = col[i + 1];
        const int s2 = col[i + 2];
        const int s3 = col[i + 3];
        const uint4 v0 = *(const uint4*)(xb + (size_t)s0 * 64 + c8);
        const uint4 v1 = *(const uint4*)(xb + (size_t)s1 * 64 + c8);
        const uint4 v2 = *(const uint4*)(xb + (size_t)s2 * 64 + c8);
        const uint4 v3 = *(const uint4*)(xb + (size_t)s3 * 64 + c8);
        ACC8(a, v0)
        ACC8(b, v1)
        ACC8(a, v2)
        ACC8(b, v3)
    }
    for (; i < end; ++i) {
        const int s = col[i];
        const uint4 v = *(const uint4*)(xb + (size_t)s * 64 + c8);
        ACC8(a, v)
    }

    const float rd = 1.0f / fmaxf((float)(end - beg), 1.0f);
    float4 lo, hi;
    lo.x = (a0 + b0) * rd; lo.y = (a1 + b1) * rd;
    lo.z = (a2 + b2) * rd; lo.w = (a3 + b3) * rd;
    hi.x = (a4 + b4) * rd; hi.y = (a5 + b5) * rd;
    hi.z = (a6 + b6) * rd; hi.w = (a7 + b7) * rd;
    float* mp = mean + (size_t)node * 64 + c8;
    *(float4*)(mp) = lo;
    *(float4*)(mp + 4) = hi;
}

// ============ update: out = xin@Ws + mean@Wn + b (opt relu), in-place safe ============
// Also emits packed-bf16 copy of the output (for the next layer's gather) if outb != null.
__global__ __launch_bounds__(256) void update_kernel(const float* __restrict__ xin,
                                                     const float* __restrict__ mean,
                                                     const float* __restrict__ Ws,
                                                     const float* __restrict__ Wn,
                                                     const float* __restrict__ bias,
                                                     float* __restrict__ out,
                                                     unsigned short* __restrict__ outb,
                                                     int N, int do_relu) {
    __shared__ float sWs[4096];
    __shared__ float sWn[4096];
    __shared__ float sb[64];
    __shared__ float sx[NPB][68];
    __shared__ float sm[NPB][68];

    const int tid = threadIdx.x;
    for (int i = tid; i < 4096; i += 256) {
        sWs[i] = Ws[i];
        sWn[i] = Wn[i];
    }
    if (tid < 64) sb[tid] = bias[tid];

    const int node0 = blockIdx.x * NPB;
    {
        const int nl = tid >> 4;
        const int c4 = (tid & 15) * 4;
        for (int r = 0; r < 2; ++r) {
            const int n = r * 16 + nl;
            const int node = node0 + n;
            float4 xv = make_float4(0.f, 0.f, 0.f, 0.f);
            float4 mv = make_float4(0.f, 0.f, 0.f, 0.f);
            if (node < N) {
                xv = *(const float4*)(xin + (size_t)node * 64 + c4);
                mv = *(const float4*)(mean + (size_t)node * 64 + c4);
            }
            *(float4*)(&sx[n][c4]) = xv;
            *(float4*)(&sm[n][c4]) = mv;
        }
    }
    __syncthreads();

    const int n = tid >> 3;
    const int j0 = (tid & 7) * 8;
    float acc[8];
#pragma unroll
    for (int jj = 0; jj < 8; jj++) acc[jj] = sb[j0 + jj];

    for (int k = 0; k < 64; k++) {
        const float xv = sx[n][k];
        const float mv = sm[n][k];
        const float* ws = &sWs[k * 64 + j0];
        const float* wn = &sWn[k * 64 + j0];
#pragma unroll
        for (int jj = 0; jj < 8; jj++) {
            acc[jj] += xv * ws[jj] + mv * wn[jj];
        }
    }

    const int node = node0 + n;
    if (node < N) {
#pragma unroll
        for (int jj = 0; jj < 8; jj++) {
            if (do_relu) acc[jj] = fmaxf(acc[jj], 0.f);
        }
        float* op = out + (size_t)node * 64 + j0;
        *(float4*)(op)     = make_float4(acc[0], acc[1], acc[2], acc[3]);
        *(float4*)(op + 4) = make_float4(acc[4], acc[5], acc[6], acc[7]);
        if (outb) {
            uint4 o;
            o.x = (unsigned)f2bf(acc[0]) | ((unsigned)f2bf(acc[1]) << 16);
            o.y = (unsigned)f2bf(acc[2]) | ((unsigned)f2bf(acc[3]) << 16);
            o.z = (unsigned)f2bf(acc[4]) | ((unsigned)f2bf(acc[5]) << 16);
            o.w = (unsigned)f2bf(acc[6]) | ((unsigned)f2bf(acc[7]) << 16);
            *(uint4*)(outb + (size_t)node * 64 + j0) = o;
        }
    }
}

extern "C" void kernel_launch(void* const* d_in, const int* in_sizes, int n_in,
                              void* d_out, int out_size, void* d_ws, size_t ws_size,
                              hipStream_t stream) {
    const float* x   = (const float*)d_in[0];
    const int*   ei  = (const int*)d_in[1];
    const float* ws1 = (const float*)d_in[2];
    const float* wn1 = (const float*)d_in[3];
    const float* b1  = (const float*)d_in[4];
    const float* ws2 = (const float*)d_in[5];
    const float* wn2 = (const float*)d_in[6];
    const float* b2  = (const float*)d_in[7];
    const float* ws3 = (const float*)d_in[8];
    const float* wn3 = (const float*)d_in[9];
    const float* b3  = (const float*)d_in[10];

    const int N = in_sizes[0] / 64;   // 100000
    const int E = in_sizes[1] / 2;    // 1600000
    const int* src = ei;
    const int* dst = ei + E;
    const int NB = (N + 255) >> 8;    // 391 buckets
    const int M  = NB * PB;           // flat counts/seg_base length

    float* out = (float*)d_out;

    auto align256 = [](size_t v) { return (v + 255) / 256 * 256; };
    char* p = (char*)d_ws;
    int* counts      = (int*)p; p += align256((size_t)M * 4);
    int* seg_base    = (int*)p; p += align256((size_t)M * 4);
    int* bsums       = (int*)p; p += align256(1024 * 4);
    int* bucket_base = (int*)p; p += align256((size_t)(NB + 1) * 4);
    int* row_start   = (int*)p; p += align256((size_t)(N + 1) * 4);
    int* pairs       = (int*)p; p += align256((size_t)E * 4);
    int* col         = (int*)p; p += align256((size_t)E * 4);
    unsigned short* xb = (unsigned short*)p; p += align256((size_t)N * 64 * 2);
    float* hbuf      = (float*)p;     // N*64 floats

    const int scan_blocks = (M + 255) / 256;      // 782 (<= 1024 for scanB)
    const int gm_blocks   = (N + 31) / 32;        // 3125
    const int upd_blocks  = (N + NPB - 1) / NPB;  // 3125
    const int cvt_blocks  = (N * 64 / 8 + 255) / 256;

    // ---- CSR build (partitioned, segment-local writes, full-chip parallel) ----
    part_hist   <<<PB, 256, 0, stream>>>(dst, counts, E, NB);
    scanA       <<<scan_blocks, 256, 0, stream>>>(counts, seg_base, bsums, M);
    scanB       <<<1, 1024, 0, stream>>>(bsums, scan_blocks);
    scanC       <<<scan_blocks, 256, 0, stream>>>(seg_base, bsums, bucket_base, M, NB, E);
    part_scatter<<<PB, 256, 0, stream>>>(src, dst, seg_base, pairs, E, NB);
    csr_finalize<<<NB, 256, 0, stream>>>(pairs, bucket_base, row_start, col, N, E);

    // ---- bf16 shadow of x ----
    to_bf16_kernel<<<cvt_blocks, 256, 0, stream>>>(x, xb, N * 64 / 8);

    // ---- layer 1: x -> hbuf(h1) [+ xb := bf16(h1)] ----
    gather_mean_kernel<<<gm_blocks, 256, 0, stream>>>(xb, col, row_start, hbuf, N);
    update_kernel<<<upd_blocks, 256, 0, stream>>>(x, hbuf, ws1, wn1, b1, hbuf, xb, N, 1);
    // ---- layer 2: hbuf(h1) -> hbuf(h2) [+ xb := bf16(h2)], mean staged in d_out ----
    gather_mean_kernel<<<gm_blocks, 256, 0, stream>>>(xb, col, row_start, out, N);
    update_kernel<<<upd_blocks, 256, 0, stream>>>(hbuf, out, ws2, wn2, b2, hbuf, xb, N, 1);
    // ---- layer 3: hbuf(h2) -> d_out (mean staged in d_out, in-place update) ----
    gather_mean_kernel<<<gm_blocks, 256, 0, stream>>>(xb, col, row_start, out, N);
    update_kernel<<<upd_blocks, 256, 0, stream>>>(hbuf, out, ws3, wn3, b3, out, nullptr, N, 0);
}

// Round 7
// 276.409 us; speedup vs baseline: 15.9131x; 1.3605x over previous
//
#include <hip/hip_runtime.h>
#include <hip/hip_bf16.h>

#define PB   512  // partition blocks: 2 blocks/CU -> full-chip parallelism

typedef short bf16x8 __attribute__((ext_vector_type(8)));
typedef float f32x4  __attribute__((ext_vector_type(4)));

__device__ __forceinline__ unsigned short f2bf(float f) {  // RNE f32->bf16
    unsigned u = __float_as_uint(f);
    u += 0x7FFFu + ((u >> 16) & 1u);
    return (unsigned short)(u >> 16);
}

// ============ CSR build: radix partition by dst>>8 (segment-local writes) ============

__global__ __launch_bounds__(256) void part_hist(const int* __restrict__ dst,
                                                 int* __restrict__ counts,
                                                 int E, int NB) {
    __shared__ int h[512];
    const int tid = threadIdx.x;
    for (int i = tid; i < NB; i += 256) h[i] = 0;
    __syncthreads();
    const int per = (E + PB - 1) / PB;
    const int s = blockIdx.x * per;
    const int e = min(E, s + per);
    for (int i = s + tid; i < e; i += 256) atomicAdd(&h[dst[i] >> 8], 1);
    __syncthreads();
    for (int i = tid; i < NB; i += 256) counts[i * PB + blockIdx.x] = h[i];
}

__global__ __launch_bounds__(256) void scanA(const int* __restrict__ in,
                                             int* __restrict__ excl,
                                             int* __restrict__ bsums, int M) {
    __shared__ int tmp[256];
    const int tid = threadIdx.x;
    const int g = blockIdx.x * 256 + tid;
    int v = (g < M) ? in[g] : 0;
    tmp[tid] = v;
    __syncthreads();
    for (int off = 1; off < 256; off <<= 1) {
        int t = (tid >= off) ? tmp[tid - off] : 0;
        __syncthreads();
        tmp[tid] += t;
        __syncthreads();
    }
    if (g < M) excl[g] = tmp[tid] - v;
    if (tid == 255) bsums[blockIdx.x] = tmp[255];
}

__global__ __launch_bounds__(1024) void scanB(int* bsums, int nb) {
    __shared__ int tmp[1024];
    const int tid = threadIdx.x;
    int v = (tid < nb) ? bsums[tid] : 0;
    tmp[tid] = v;
    __syncthreads();
    for (int off = 1; off < 1024; off <<= 1) {
        int t = (tid >= off) ? tmp[tid - off] : 0;
        __syncthreads();
        tmp[tid] += t;
        __syncthreads();
    }
    if (tid < nb) bsums[tid] = tmp[tid] - v;  // exclusive
}

__global__ __launch_bounds__(256) void scanC(int* __restrict__ seg_base,
                                             const int* __restrict__ bsums,
                                             int* __restrict__ bucket_base,
                                             int M, int NB, int E) {
    const int g = blockIdx.x * 256 + threadIdx.x;
    if (g < M) {
        const int v = seg_base[g] + bsums[g >> 8];
        seg_base[g] = v;
        if ((g & (PB - 1)) == 0) bucket_base[g / PB] = v;
    }
    if (g == 0) bucket_base[NB] = E;
}

__global__ __launch_bounds__(256) void part_scatter(const int* __restrict__ src,
                                                    const int* __restrict__ dst,
                                                    const int* __restrict__ seg_base,
                                                    int* __restrict__ pairs,
                                                    int E, int NB) {
    __shared__ int cur[512];
    const int tid = threadIdx.x;
    for (int i = tid; i < NB; i += 256) cur[i] = seg_base[i * PB + blockIdx.x];
    __syncthreads();
    const int per = (E + PB - 1) / PB;
    const int s = blockIdx.x * per;
    const int e = min(E, s + per);
    for (int i = s + tid; i < e; i += 256) {
        const int d = dst[i];
        const int b = d >> 8;
        const int slot = atomicAdd(&cur[b], 1);
        pairs[slot] = src[i] | ((d & 255) << 20);
    }
}

__global__ __launch_bounds__(256) void csr_finalize(const int* __restrict__ pairs,
                                                    const int* __restrict__ bucket_base,
                                                    int* __restrict__ row_start,
                                                    int* __restrict__ col,
                                                    int N, int E) {
    __shared__ int h[256];
    __shared__ int tmp[256];
    __shared__ int cur[256];
    const int tid = threadIdx.x;
    const int b = blockIdx.x;
    const int node0 = b << 8;
    const int pbeg = bucket_base[b];
    const int pend = bucket_base[b + 1];
    h[tid] = 0;
    __syncthreads();
    for (int i = pbeg + tid; i < pend; i += 256)
        atomicAdd(&h[(pairs[i] >> 20) & 255], 1);
    __syncthreads();
    const int v = h[tid];
    tmp[tid] = v;
    __syncthreads();
    for (int off = 1; off < 256; off <<= 1) {
        int t = (tid >= off) ? tmp[tid - off] : 0;
        __syncthreads();
        tmp[tid] += t;
        __syncthreads();
    }
    const int excl = tmp[tid] - v;
    cur[tid] = pbeg + excl;
    if (node0 + tid < N) row_start[node0 + tid] = pbeg + excl;
    if (b == 0 && tid == 0) row_start[N] = E;
    __syncthreads();
    for (int i = pbeg + tid; i < pend; i += 256) {
        const int p = pairs[i];
        const int slot = atomicAdd(&cur[(p >> 20) & 255], 1);
        col[slot] = p & 0xFFFFF;
    }
}

// ============ f32 -> bf16 shadow copy (RNE), 8 elems/thread ============
__global__ __launch_bounds__(256) void to_bf16_kernel(const float* __restrict__ in,
                                                      unsigned short* __restrict__ out,
                                                      int n8) {
    const int g = blockIdx.x * 256 + threadIdx.x;
    if (g >= n8) return;
    const float4 v0 = *(const float4*)(in + (size_t)g * 8);
    const float4 v1 = *(const float4*)(in + (size_t)g * 8 + 4);
    uint4 o;
    o.x = (unsigned)f2bf(v0.x) | ((unsigned)f2bf(v0.y) << 16);
    o.y = (unsigned)f2bf(v0.z) | ((unsigned)f2bf(v0.w) << 16);
    o.z = (unsigned)f2bf(v1.x) | ((unsigned)f2bf(v1.y) << 16);
    o.w = (unsigned)f2bf(v1.z) | ((unsigned)f2bf(v1.w) << 16);
    *(uint4*)(out + (size_t)g * 8) = o;
}

// ============ pack weights: B = [Ws;Wn] (128x64) -> bf16, MFMA B-frag swizzle ============
// Layout: bswp[((s*4+t)*64 + lane)*8 + j] = B[s*32 + (lane>>4)*8 + j][t*16 + (lane&15)]
__global__ __launch_bounds__(256) void pack_w_kernel(const float* __restrict__ Ws,
                                                     const float* __restrict__ Wn,
                                                     unsigned short* __restrict__ bswp) {
    const int i = blockIdx.x * 256 + threadIdx.x;  // 0..8191
    if (i >= 8192) return;
    const int j = i & 7;
    const int L = (i >> 3) & 63;
    const int t = (i >> 9) & 3;
    const int s = i >> 11;
    const int k = s * 32 + ((L >> 4) << 3) + j;
    const int n = t * 16 + (L & 15);
    const float v = (k < 64) ? Ws[k * 64 + n] : Wn[(k - 64) * 64 + n];
    bswp[i] = f2bf(v);
}

// ============ gather-mean over bf16 features -> bf16 mean ============
// 8 lanes per node (8 bf16 channels each, 16B loads), 32 nodes/block,
// edge loop x4 unroll into two f32 accumulator banks.
#define ACC8(A, V)                                                    \
    A##0 += __uint_as_float((V).x << 16);                             \
    A##1 += __uint_as_float((V).x & 0xFFFF0000u);                     \
    A##2 += __uint_as_float((V).y << 16);                             \
    A##3 += __uint_as_float((V).y & 0xFFFF0000u);                     \
    A##4 += __uint_as_float((V).z << 16);                             \
    A##5 += __uint_as_float((V).z & 0xFFFF0000u);                     \
    A##6 += __uint_as_float((V).w << 16);                             \
    A##7 += __uint_as_float((V).w & 0xFFFF0000u);

__global__ __launch_bounds__(256) void gather_mean_kernel(
        const unsigned short* __restrict__ xb, const int* __restrict__ col,
        const int* __restrict__ row_start, unsigned short* __restrict__ meanb, int N) {
    const int tid = threadIdx.x;
    const int node = blockIdx.x * 32 + (tid >> 3);
    const int c8 = (tid & 7) * 8;
    if (node >= N) return;
    const int beg = row_start[node];
    const int end = row_start[node + 1];

    float a0 = 0.f, a1 = 0.f, a2 = 0.f, a3 = 0.f, a4 = 0.f, a5 = 0.f, a6 = 0.f, a7 = 0.f;
    float b0 = 0.f, b1 = 0.f, b2 = 0.f, b3 = 0.f, b4 = 0.f, b5 = 0.f, b6 = 0.f, b7 = 0.f;

    int i = beg;
    for (; i + 4 <= end; i += 4) {
        const int s0 = col[i + 0];
        const int s1 = col[i + 1];
        const int s2 = col[i + 2];
        const int s3 = col[i + 3];
        const uint4 v0 = *(const uint4*)(xb + (size_t)s0 * 64 + c8);
        const uint4 v1 = *(const uint4*)(xb + (size_t)s1 * 64 + c8);
        const uint4 v2 = *(const uint4*)(xb + (size_t)s2 * 64 + c8);
        const uint4 v3 = *(const uint4*)(xb + (size_t)s3 * 64 + c8);
        ACC8(a, v0)
        ACC8(b, v1)
        ACC8(a, v2)
        ACC8(b, v3)
    }
    for (; i < end; ++i) {
        const int s = col[i];
        const uint4 v = *(const uint4*)(xb + (size_t)s * 64 + c8);
        ACC8(a, v)
    }

    const float rd = 1.0f / fmaxf((float)(end - beg), 1.0f);
    const float m0 = (a0 + b0) * rd, m1 = (a1 + b1) * rd;
    const float m2 = (a2 + b2) * rd, m3 = (a3 + b3) * rd;
    const float m4 = (a4 + b4) * rd, m5 = (a5 + b5) * rd;
    const float m6 = (a6 + b6) * rd, m7 = (a7 + b7) * rd;
    uint4 o;
    o.x = (unsigned)f2bf(m0) | ((unsigned)f2bf(m1) << 16);
    o.y = (unsigned)f2bf(m2) | ((unsigned)f2bf(m3) << 16);
    o.z = (unsigned)f2bf(m4) | ((unsigned)f2bf(m5) << 16);
    o.w = (unsigned)f2bf(m6) | ((unsigned)f2bf(m7) << 16);
    *(uint4*)(meanb + (size_t)node * 64 + c8) = o;
}

// ============ MFMA update: C[N,64] = [xb|meanb]@[Ws;Wn] + b (opt relu) ============
// 64 nodes/block, 4 waves; wave w -> nodes node0+w*16..+15, all 64 cols.
// No LDS, no barrier. B-frags from pre-swizzled global (L1-resident, 16 KB).
// In-place safe on xb: each wave reads/writes only its own 16 node rows.
__global__ __launch_bounds__(256) void mfma_update_kernel(
        const unsigned short* __restrict__ xb,
        const unsigned short* __restrict__ meanb,
        const unsigned short* __restrict__ bswp,
        const float* __restrict__ bias,
        float* __restrict__ outf,            // may be null
        unsigned short* __restrict__ outb,   // may be null; may alias xb
        int N, int do_relu) {
    const int tid  = threadIdx.x;
    const int lane = tid & 63;
    const int wave = tid >> 6;
    const int m    = lane & 15;
    const int quad = lane >> 4;
    const int node0 = blockIdx.x * 64 + wave * 16;

    int arow = node0 + m;
    if (arow >= N) arow = N - 1;             // clamp: avoids OOB, stores are guarded
    const unsigned short* xr = xb    + (size_t)arow * 64 + quad * 8;
    const unsigned short* mr = meanb + (size_t)arow * 64 + quad * 8;

    f32x4 acc[4];
#pragma unroll
    for (int t = 0; t < 4; ++t) {
        const float b = bias[t * 16 + m];
        acc[t] = (f32x4){b, b, b, b};
    }

#pragma unroll
    for (int s = 0; s < 4; ++s) {
        bf16x8 a;
        if (s < 2) a = *(const bf16x8*)(xr + s * 32);
        else       a = *(const bf16x8*)(mr + (s - 2) * 32);
#pragma unroll
        for (int t = 0; t < 4; ++t) {
            const bf16x8 bf = *(const bf16x8*)(bswp + (((s * 4 + t) * 64 + lane) << 3));
            acc[t] = __builtin_amdgcn_mfma_f32_16x16x32_bf16(a, bf, acc[t], 0, 0, 0);
        }
    }

    // C/D: col = t*16 + (lane&15), row(node) = node0 + quad*4 + r
#pragma unroll
    for (int t = 0; t < 4; ++t) {
        const int colg = t * 16 + m;
#pragma unroll
        for (int r = 0; r < 4; ++r) {
            const int node = node0 + quad * 4 + r;
            if (node < N) {
                float v = acc[t][r];
                if (do_relu) v = fmaxf(v, 0.f);
                if (outf) outf[(size_t)node * 64 + colg] = v;
                if (outb) outb[(size_t)node * 64 + colg] = f2bf(v);
            }
        }
    }
}

extern "C" void kernel_launch(void* const* d_in, const int* in_sizes, int n_in,
                              void* d_out, int out_size, void* d_ws, size_t ws_size,
                              hipStream_t stream) {
    const float* x   = (const float*)d_in[0];
    const int*   ei  = (const int*)d_in[1];
    const float* ws1 = (const float*)d_in[2];
    const float* wn1 = (const float*)d_in[3];
    const float* b1  = (const float*)d_in[4];
    const float* ws2 = (const float*)d_in[5];
    const float* wn2 = (const float*)d_in[6];
    const float* b2  = (const float*)d_in[7];
    const float* ws3 = (const float*)d_in[8];
    const float* wn3 = (const float*)d_in[9];
    const float* b3  = (const float*)d_in[10];

    const int N = in_sizes[0] / 64;   // 100000
    const int E = in_sizes[1] / 2;    // 1600000
    const int* src = ei;
    const int* dst = ei + E;
    const int NB = (N + 255) >> 8;    // 391 buckets
    const int M  = NB * PB;

    float* out = (float*)d_out;

    auto align256 = [](size_t v) { return (v + 255) / 256 * 256; };
    char* p = (char*)d_ws;
    int* counts      = (int*)p; p += align256((size_t)M * 4);
    int* seg_base    = (int*)p; p += align256((size_t)M * 4);
    int* bsums       = (int*)p; p += align256(1024 * 4);
    int* bucket_base = (int*)p; p += align256((size_t)(NB + 1) * 4);
    int* row_start   = (int*)p; p += align256((size_t)(N + 1) * 4);
    int* pairs       = (int*)p; p += align256((size_t)E * 4);
    int* col         = (int*)p; p += align256((size_t)E * 4);
    unsigned short* xb    = (unsigned short*)p; p += align256((size_t)N * 64 * 2);
    unsigned short* meanb = (unsigned short*)p; p += align256((size_t)N * 64 * 2);
    unsigned short* bw1   = (unsigned short*)p; p += align256(8192 * 2);
    unsigned short* bw2   = (unsigned short*)p; p += align256(8192 * 2);
    unsigned short* bw3   = (unsigned short*)p; p += align256(8192 * 2);

    const int scan_blocks = (M + 255) / 256;
    const int gm_blocks   = (N + 31) / 32;        // 3125
    const int upd_blocks  = (N + 63) / 64;        // 1563
    const int cvt_blocks  = (N * 64 / 8 + 255) / 256;

    // ---- CSR build (partitioned, segment-local writes, full-chip parallel) ----
    part_hist   <<<PB, 256, 0, stream>>>(dst, counts, E, NB);
    scanA       <<<scan_blocks, 256, 0, stream>>>(counts, seg_base, bsums, M);
    scanB       <<<1, 1024, 0, stream>>>(bsums, scan_blocks);
    scanC       <<<scan_blocks, 256, 0, stream>>>(seg_base, bsums, bucket_base, M, NB, E);
    part_scatter<<<PB, 256, 0, stream>>>(src, dst, seg_base, pairs, E, NB);
    csr_finalize<<<NB, 256, 0, stream>>>(pairs, bucket_base, row_start, col, N, E);

    // ---- weight packs + bf16 shadow of x ----
    pack_w_kernel<<<32, 256, 0, stream>>>(ws1, wn1, bw1);
    pack_w_kernel<<<32, 256, 0, stream>>>(ws2, wn2, bw2);
    pack_w_kernel<<<32, 256, 0, stream>>>(ws3, wn3, bw3);
    to_bf16_kernel<<<cvt_blocks, 256, 0, stream>>>(x, xb, N * 64 / 8);

    // ---- layer 1: xb -> xb (bf16 h1) ----
    gather_mean_kernel<<<gm_blocks, 256, 0, stream>>>(xb, col, row_start, meanb, N);
    mfma_update_kernel<<<upd_blocks, 256, 0, stream>>>(xb, meanb, bw1, b1, nullptr, xb, N, 1);
    // ---- layer 2: xb -> xb (bf16 h2) ----
    gather_mean_kernel<<<gm_blocks, 256, 0, stream>>>(xb, col, row_start, meanb, N);
    mfma_update_kernel<<<upd_blocks, 256, 0, stream>>>(xb, meanb, bw2, b2, nullptr, xb, N, 1);
    // ---- layer 3: xb -> d_out (f32) ----
    gather_mean_kernel<<<gm_blocks, 256, 0, stream>>>(xb, col, row_start, meanb, N);
    mfma_update_kernel<<<upd_blocks, 256, 0, stream>>>(xb, meanb, bw3, b3, out, nullptr, N, 0);
}

// Round 8
// 272.460 us; speedup vs baseline: 16.1437x; 1.0145x over previous
//
#include <hip/hip_runtime.h>
#include <hip/hip_bf16.h>

#define PB   512  // partition blocks: 2 blocks/CU -> full-chip parallelism

typedef short bf16x8 __attribute__((ext_vector_type(8)));
typedef float f32x4  __attribute__((ext_vector_type(4)));

__device__ __forceinline__ unsigned short f2bf(float f) {  // RNE f32->bf16
    unsigned u = __float_as_uint(f);
    u += 0x7FFFu + ((u >> 16) & 1u);
    return (unsigned short)(u >> 16);
}

// ============ CSR build: radix partition by dst>>8 (segment-local writes) ============

__global__ __launch_bounds__(256) void part_hist(const int* __restrict__ dst,
                                                 int* __restrict__ counts,
                                                 int E, int NB) {
    __shared__ int h[512];
    const int tid = threadIdx.x;
    for (int i = tid; i < NB; i += 256) h[i] = 0;
    __syncthreads();
    const int per = (E + PB - 1) / PB;
    const int s = blockIdx.x * per;
    const int e = min(E, s + per);
    for (int i = s + tid; i < e; i += 256) atomicAdd(&h[dst[i] >> 8], 1);
    __syncthreads();
    for (int i = tid; i < NB; i += 256) counts[i * PB + blockIdx.x] = h[i];
}

__global__ __launch_bounds__(256) void scanA(const int* __restrict__ in,
                                             int* __restrict__ excl,
                                             int* __restrict__ bsums, int M) {
    __shared__ int tmp[256];
    const int tid = threadIdx.x;
    const int g = blockIdx.x * 256 + tid;
    int v = (g < M) ? in[g] : 0;
    tmp[tid] = v;
    __syncthreads();
    for (int off = 1; off < 256; off <<= 1) {
        int t = (tid >= off) ? tmp[tid - off] : 0;
        __syncthreads();
        tmp[tid] += t;
        __syncthreads();
    }
    if (g < M) excl[g] = tmp[tid] - v;
    if (tid == 255) bsums[blockIdx.x] = tmp[255];
}

__global__ __launch_bounds__(1024) void scanB(int* bsums, int nb) {
    __shared__ int tmp[1024];
    const int tid = threadIdx.x;
    int v = (tid < nb) ? bsums[tid] : 0;
    tmp[tid] = v;
    __syncthreads();
    for (int off = 1; off < 1024; off <<= 1) {
        int t = (tid >= off) ? tmp[tid - off] : 0;
        __syncthreads();
        tmp[tid] += t;
        __syncthreads();
    }
    if (tid < nb) bsums[tid] = tmp[tid] - v;  // exclusive
}

__global__ __launch_bounds__(256) void scanC(int* __restrict__ seg_base,
                                             const int* __restrict__ bsums,
                                             int* __restrict__ bucket_base,
                                             int M, int NB, int E) {
    const int g = blockIdx.x * 256 + threadIdx.x;
    if (g < M) {
        const int v = seg_base[g] + bsums[g >> 8];
        seg_base[g] = v;
        if ((g & (PB - 1)) == 0) bucket_base[g / PB] = v;
    }
    if (g == 0) bucket_base[NB] = E;
}

__global__ __launch_bounds__(256) void part_scatter(const int* __restrict__ src,
                                                    const int* __restrict__ dst,
                                                    const int* __restrict__ seg_base,
                                                    int* __restrict__ pairs,
                                                    int E, int NB) {
    __shared__ int cur[512];
    const int tid = threadIdx.x;
    for (int i = tid; i < NB; i += 256) cur[i] = seg_base[i * PB + blockIdx.x];
    __syncthreads();
    const int per = (E + PB - 1) / PB;
    const int s = blockIdx.x * per;
    const int e = min(E, s + per);
    for (int i = s + tid; i < e; i += 256) {
        const int d = dst[i];
        const int b = d >> 8;
        const int slot = atomicAdd(&cur[b], 1);
        pairs[slot] = src[i] | ((d & 255) << 20);
    }
}

__global__ __launch_bounds__(256) void csr_finalize(const int* __restrict__ pairs,
                                                    const int* __restrict__ bucket_base,
                                                    int* __restrict__ row_start,
                                                    int* __restrict__ col,
                                                    int N, int E) {
    __shared__ int h[256];
    __shared__ int tmp[256];
    __shared__ int cur[256];
    const int tid = threadIdx.x;
    const int b = blockIdx.x;
    const int node0 = b << 8;
    const int pbeg = bucket_base[b];
    const int pend = bucket_base[b + 1];
    h[tid] = 0;
    __syncthreads();
    for (int i = pbeg + tid; i < pend; i += 256)
        atomicAdd(&h[(pairs[i] >> 20) & 255], 1);
    __syncthreads();
    const int v = h[tid];
    tmp[tid] = v;
    __syncthreads();
    for (int off = 1; off < 256; off <<= 1) {
        int t = (tid >= off) ? tmp[tid - off] : 0;
        __syncthreads();
        tmp[tid] += t;
        __syncthreads();
    }
    const int excl = tmp[tid] - v;
    cur[tid] = pbeg + excl;
    if (node0 + tid < N) row_start[node0 + tid] = pbeg + excl;
    if (b == 0 && tid == 0) row_start[N] = E;
    __syncthreads();
    for (int i = pbeg + tid; i < pend; i += 256) {
        const int p = pairs[i];
        const int slot = atomicAdd(&cur[(p >> 20) & 255], 1);
        col[slot] = p & 0xFFFFF;
    }
}

// ============ f32 -> bf16 shadow copy (RNE), 8 elems/thread ============
__global__ __launch_bounds__(256) void to_bf16_kernel(const float* __restrict__ in,
                                                      unsigned short* __restrict__ out,
                                                      int n8) {
    const int g = blockIdx.x * 256 + threadIdx.x;
    if (g >= n8) return;
    const float4 v0 = *(const float4*)(in + (size_t)g * 8);
    const float4 v1 = *(const float4*)(in + (size_t)g * 8 + 4);
    uint4 o;
    o.x = (unsigned)f2bf(v0.x) | ((unsigned)f2bf(v0.y) << 16);
    o.y = (unsigned)f2bf(v0.z) | ((unsigned)f2bf(v0.w) << 16);
    o.z = (unsigned)f2bf(v1.x) | ((unsigned)f2bf(v1.y) << 16);
    o.w = (unsigned)f2bf(v1.z) | ((unsigned)f2bf(v1.w) << 16);
    *(uint4*)(out + (size_t)g * 8) = o;
}

// ============ pack all 3 layers' weights: B = [Ws;Wn] (128x64) -> bf16, B-frag swizzle ===
// bw[((s*4+t)*64 + lane)*8 + j] = B[s*32 + (lane>>4)*8 + j][t*16 + (lane&15)]
__global__ __launch_bounds__(256) void pack_w3_kernel(
        const float* __restrict__ Ws1, const float* __restrict__ Wn1,
        const float* __restrict__ Ws2, const float* __restrict__ Wn2,
        const float* __restrict__ Ws3, const float* __restrict__ Wn3,
        unsigned short* __restrict__ bw) {
    const int i = blockIdx.x * 256 + threadIdx.x;  // 0..24575
    if (i >= 3 * 8192) return;
    const int w = i >> 13;
    const int r = i & 8191;
    const float* Ws = (w == 0) ? Ws1 : (w == 1) ? Ws2 : Ws3;
    const float* Wn = (w == 0) ? Wn1 : (w == 1) ? Wn2 : Wn3;
    const int j = r & 7;
    const int L = (r >> 3) & 63;
    const int t = (r >> 9) & 3;
    const int s = r >> 11;
    const int k = s * 32 + ((L >> 4) << 3) + j;
    const int n = t * 16 + (L & 15);
    const float v = (k < 64) ? Ws[k * 64 + n] : Wn[(k - 64) * 64 + n];
    bw[i] = f2bf(v);
}

// ============ fused layer: gather-mean (LDS) + MFMA update ============
// 64 nodes/block, 256 threads.
// Phase 1: 8 lanes/node, 2 rounds of 32 nodes; bf16 mean -> smean[64][72] (pad:
//   144B row stride -> only free 2-way bank aliasing on A-frag reads).
// Phase 2: wave w -> nodes node0+w*16..+15; A-frags: self from global xin rows,
//   mean from LDS; B-frags from pre-swizzled global bswp (L1-resident).
// xin is read (own rows + random neighbor rows); outb MUST NOT alias xin.
#define ACC8(A, V)                                                    \
    A##0 += __uint_as_float((V).x << 16);                             \
    A##1 += __uint_as_float((V).x & 0xFFFF0000u);                     \
    A##2 += __uint_as_float((V).y << 16);                             \
    A##3 += __uint_as_float((V).y & 0xFFFF0000u);                     \
    A##4 += __uint_as_float((V).z << 16);                             \
    A##5 += __uint_as_float((V).z & 0xFFFF0000u);                     \
    A##6 += __uint_as_float((V).w << 16);                             \
    A##7 += __uint_as_float((V).w & 0xFFFF0000u);

__global__ __launch_bounds__(256) void sage_fused_kernel(
        const unsigned short* __restrict__ xin, const int* __restrict__ col,
        const int* __restrict__ row_start,
        const unsigned short* __restrict__ bswp, const float* __restrict__ bias,
        unsigned short* __restrict__ outb,   // may be null; must not alias xin
        float* __restrict__ outf,            // may be null
        int N, int do_relu) {
    __shared__ __align__(16) unsigned short smean[64][72];

    const int tid = threadIdx.x;
    const int node0 = blockIdx.x * 64;

    // ---- phase 1: gather means into LDS ----
    for (int r = 0; r < 2; ++r) {
        const int nl = r * 32 + (tid >> 3);
        const int node = node0 + nl;
        const int c8 = (tid & 7) * 8;
        float a0 = 0.f, a1 = 0.f, a2 = 0.f, a3 = 0.f, a4 = 0.f, a5 = 0.f, a6 = 0.f, a7 = 0.f;
        float b0 = 0.f, b1 = 0.f, b2 = 0.f, b3 = 0.f, b4 = 0.f, b5 = 0.f, b6 = 0.f, b7 = 0.f;
        float rd = 0.f;
        if (node < N) {
            const int beg = row_start[node];
            const int end = row_start[node + 1];
            int i = beg;
            for (; i + 4 <= end; i += 4) {
                const int s0 = col[i + 0];
                const int s1 = col[i + 1];
                const int s2 = col[i + 2];
                const int s3 = col[i + 3];
                const uint4 v0 = *(const uint4*)(xin + (size_t)s0 * 64 + c8);
                const uint4 v1 = *(const uint4*)(xin + (size_t)s1 * 64 + c8);
                const uint4 v2 = *(const uint4*)(xin + (size_t)s2 * 64 + c8);
                const uint4 v3 = *(const uint4*)(xin + (size_t)s3 * 64 + c8);
                ACC8(a, v0)
                ACC8(b, v1)
                ACC8(a, v2)
                ACC8(b, v3)
            }
            for (; i < end; ++i) {
                const int s = col[i];
                const uint4 v = *(const uint4*)(xin + (size_t)s * 64 + c8);
                ACC8(a, v)
            }
            rd = 1.0f / fmaxf((float)(end - beg), 1.0f);
        }
        const float m0 = (a0 + b0) * rd, m1 = (a1 + b1) * rd;
        const float m2 = (a2 + b2) * rd, m3 = (a3 + b3) * rd;
        const float m4 = (a4 + b4) * rd, m5 = (a5 + b5) * rd;
        const float m6 = (a6 + b6) * rd, m7 = (a7 + b7) * rd;
        uint4 o;
        o.x = (unsigned)f2bf(m0) | ((unsigned)f2bf(m1) << 16);
        o.y = (unsigned)f2bf(m2) | ((unsigned)f2bf(m3) << 16);
        o.z = (unsigned)f2bf(m4) | ((unsigned)f2bf(m5) << 16);
        o.w = (unsigned)f2bf(m6) | ((unsigned)f2bf(m7) << 16);
        *(uint4*)(&smean[nl][c8]) = o;
    }
    __syncthreads();

    // ---- phase 2: MFMA update ----
    const int lane = tid & 63;
    const int wave = tid >> 6;
    const int m    = lane & 15;
    const int quad = lane >> 4;
    const int nw0  = node0 + wave * 16;

    int arow = nw0 + m;
    if (arow >= N) arow = N - 1;             // clamp; stores are guarded
    const unsigned short* xr = xin + (size_t)arow * 64 + quad * 8;

    f32x4 acc[4];
#pragma unroll
    for (int t = 0; t < 4; ++t) {
        const float b = bias[t * 16 + m];
        acc[t] = (f32x4){b, b, b, b};
    }

#pragma unroll
    for (int s = 0; s < 4; ++s) {
        bf16x8 a;
        if (s < 2) a = *(const bf16x8*)(xr + s * 32);
        else       a = *(const bf16x8*)(&smean[wave * 16 + m][(s - 2) * 32 + quad * 8]);
#pragma unroll
        for (int t = 0; t < 4; ++t) {
            const bf16x8 bf = *(const bf16x8*)(bswp + (((s * 4 + t) * 64 + lane) << 3));
            acc[t] = __builtin_amdgcn_mfma_f32_16x16x32_bf16(a, bf, acc[t], 0, 0, 0);
        }
    }

    // C/D: col = t*16 + m, row(node) = nw0 + quad*4 + r
#pragma unroll
    for (int t = 0; t < 4; ++t) {
        const int colg = t * 16 + m;
#pragma unroll
        for (int r = 0; r < 4; ++r) {
            const int node = nw0 + quad * 4 + r;
            if (node < N) {
                float v = acc[t][r];
                if (do_relu) v = fmaxf(v, 0.f);
                if (outf) outf[(size_t)node * 64 + colg] = v;
                if (outb) outb[(size_t)node * 64 + colg] = f2bf(v);
            }
        }
    }
}

extern "C" void kernel_launch(void* const* d_in, const int* in_sizes, int n_in,
                              void* d_out, int out_size, void* d_ws, size_t ws_size,
                              hipStream_t stream) {
    const float* x   = (const float*)d_in[0];
    const int*   ei  = (const int*)d_in[1];
    const float* ws1 = (const float*)d_in[2];
    const float* wn1 = (const float*)d_in[3];
    const float* b1  = (const float*)d_in[4];
    const float* ws2 = (const float*)d_in[5];
    const float* wn2 = (const float*)d_in[6];
    const float* b2  = (const float*)d_in[7];
    const float* ws3 = (const float*)d_in[8];
    const float* wn3 = (const float*)d_in[9];
    const float* b3  = (const float*)d_in[10];

    const int N = in_sizes[0] / 64;   // 100000
    const int E = in_sizes[1] / 2;    // 1600000
    const int* src = ei;
    const int* dst = ei + E;
    const int NB = (N + 255) >> 8;    // 391 buckets
    const int M  = NB * PB;

    float* out = (float*)d_out;

    auto align256 = [](size_t v) { return (v + 255) / 256 * 256; };
    char* p = (char*)d_ws;
    int* counts      = (int*)p; p += align256((size_t)M * 4);
    int* seg_base    = (int*)p; p += align256((size_t)M * 4);
    int* bsums       = (int*)p; p += align256(1024 * 4);
    int* bucket_base = (int*)p; p += align256((size_t)(NB + 1) * 4);
    int* row_start   = (int*)p; p += align256((size_t)(N + 1) * 4);
    int* pairs       = (int*)p; p += align256((size_t)E * 4);
    int* col         = (int*)p; p += align256((size_t)E * 4);
    unsigned short* xb  = (unsigned short*)p; p += align256((size_t)N * 64 * 2);
    unsigned short* xb2 = (unsigned short*)p; p += align256((size_t)N * 64 * 2);
    unsigned short* bw  = (unsigned short*)p; p += align256(3 * 8192 * 2);

    const int scan_blocks = (M + 255) / 256;
    const int fused_blocks = (N + 63) / 64;       // 1563
    const int cvt_blocks  = (N * 64 / 8 + 255) / 256;

    // ---- CSR build (partitioned, segment-local writes, full-chip parallel) ----
    part_hist   <<<PB, 256, 0, stream>>>(dst, counts, E, NB);
    scanA       <<<scan_blocks, 256, 0, stream>>>(counts, seg_base, bsums, M);
    scanB       <<<1, 1024, 0, stream>>>(bsums, scan_blocks);
    scanC       <<<scan_blocks, 256, 0, stream>>>(seg_base, bsums, bucket_base, M, NB, E);
    part_scatter<<<PB, 256, 0, stream>>>(src, dst, seg_base, pairs, E, NB);
    csr_finalize<<<NB, 256, 0, stream>>>(pairs, bucket_base, row_start, col, N, E);

    // ---- weight packs (one launch) + bf16 shadow of x ----
    pack_w3_kernel<<<96, 256, 0, stream>>>(ws1, wn1, ws2, wn2, ws3, wn3, bw);
    to_bf16_kernel<<<cvt_blocks, 256, 0, stream>>>(x, xb, N * 64 / 8);

    // ---- 3 fused layers (ping-pong xb <-> xb2) ----
    sage_fused_kernel<<<fused_blocks, 256, 0, stream>>>(xb,  col, row_start, bw,          b1, xb2,     nullptr, N, 1);
    sage_fused_kernel<<<fused_blocks, 256, 0, stream>>>(xb2, col, row_start, bw + 8192,   b2, xb,      nullptr, N, 1);
    sage_fused_kernel<<<fused_blocks, 256, 0, stream>>>(xb,  col, row_start, bw + 16384,  b3, nullptr, out,     N, 0);
}